// Round 13
// baseline (236.228 us; speedup 1.0000x reference)
//
#include <hip/hip_runtime.h>
#include <hip/hip_bf16.h>
#include <math.h>

#define TSEQ 4096
#define DMODEL 768
#define DFF 3072
#define NHEADS 12
#define HDIM 64

typedef __attribute__((ext_vector_type(8))) short short8;
typedef __attribute__((ext_vector_type(4))) float f32x4;
typedef __attribute__((ext_vector_type(16))) float f32x16;
typedef __attribute__((ext_vector_type(4))) unsigned int u32x4;
typedef unsigned short ushort;
typedef unsigned int uint;

typedef __attribute__((address_space(1))) ushort as1_ushort;
typedef __attribute__((address_space(3))) ushort as3_ushort;

__device__ __forceinline__ void gl_lds16(const ushort* g, const ushort* l) {
    __builtin_amdgcn_global_load_lds((as1_ushort*)(uintptr_t)g,
                                     (as3_ushort*)(uint)(uintptr_t)l, 16, 0, 0);
}

__device__ __forceinline__ ushort f2bf(float f) {
    union { float f; unsigned i; } c; c.f = f;
    unsigned x = c.i;
    unsigned r = x + 0x7FFFu + ((x >> 16) & 1u);
    return (ushort)(r >> 16);
}
__device__ __forceinline__ float asf(uint u) {
    union { unsigned i; float f; } c; c.i = u; return c.f;
}
// tanh-form GELU
__device__ __forceinline__ float gelu_fast(float v) {
    float y = v * (0.7978845608f + 0.03567740814f * v * v);
    float u = exp2f(y * -2.8853900817779268f);
    float r;
    asm("v_rcp_f32 %0, %1" : "=v"(r) : "v"(1.f + u));
    return v * r;
}

// ---------------- LayerNorm * 0.5 -> bf16 ----------------
__global__ __launch_bounds__(256) void ln_half_kernel(
    const float* __restrict__ x, const float* __restrict__ g,
    const float* __restrict__ b, ushort* __restrict__ out)
{
    int row = blockIdx.x;
    const float* xr = x + (size_t)row * DMODEL;
    float v[3];
    float s = 0.f, s2 = 0.f;
    #pragma unroll
    for (int i = 0; i < 3; i++) {
        v[i] = xr[threadIdx.x + 256 * i];
        s += v[i]; s2 += v[i] * v[i];
    }
    #pragma unroll
    for (int m = 1; m < 64; m <<= 1) { s += __shfl_xor(s, m, 64); s2 += __shfl_xor(s2, m, 64); }
    __shared__ float ss[4], ss2[4];
    int wid = threadIdx.x >> 6;
    if ((threadIdx.x & 63) == 0) { ss[wid] = s; ss2[wid] = s2; }
    __syncthreads();
    s = ss[0] + ss[1] + ss[2] + ss[3];
    s2 = ss2[0] + ss2[1] + ss2[2] + ss2[3];
    float mu = s * (1.f / DMODEL);
    float var = s2 * (1.f / DMODEL) - mu * mu;
    float rs = rsqrtf(var + 1e-5f);
    #pragma unroll
    for (int i = 0; i < 3; i++) {
        int c = threadIdx.x + 256 * i;
        float h = (v[i] - mu) * rs * g[c] + b[c];
        out[(size_t)row * DMODEL + c] = f2bf(h * 0.5f);
    }
}

// ---------------- transpose + cast: in [K,N] f32 -> out [N,K] bf16 ----------------
__global__ __launch_bounds__(256) void transpose_cast_kernel(
    const float* __restrict__ in, ushort* __restrict__ out, int K, int N)
{
    __shared__ float tile[32][33];
    int k0 = blockIdx.x * 32, n0 = blockIdx.y * 32;
    int c = threadIdx.x & 31, r0 = threadIdx.x >> 5;
    #pragma unroll
    for (int i = 0; i < 4; i++) {
        int r = r0 + i * 8;
        tile[r][c] = in[(size_t)(k0 + r) * N + n0 + c];
    }
    __syncthreads();
    #pragma unroll
    for (int i = 0; i < 4; i++) {
        int r = r0 + i * 8;
        out[(size_t)(n0 + r) * K + k0 + c] = f2bf(tile[c][r]);
    }
}

// ---------------- V transpose: qkvb [T,2304] (V cols 1536..2303) -> vT [768][T] bf16 ----------------
__global__ __launch_bounds__(256) void vtrans_kernel(
    const ushort* __restrict__ qkvb, ushort* __restrict__ vT)
{
    __shared__ ushort tile[64][72];
    int t0 = blockIdx.x * 64, d0 = blockIdx.y * 64;
    int tid = threadIdx.x;
    int r = tid >> 2, c = (tid & 3) * 16;
    const ushort* src = qkvb + (size_t)(t0 + r) * 2304 + 1536 + d0 + c;
    *(short8*)&tile[r][c]     = *(const short8*)src;
    *(short8*)&tile[r][c + 8] = *(const short8*)(src + 8);
    __syncthreads();
    int d = tid & 63, gq = tid >> 6;
    short8 w0, w1;
    #pragma unroll
    for (int i = 0; i < 8; i++) w0[i] = (short)tile[gq * 16 + i][d];
    #pragma unroll
    for (int i = 0; i < 8; i++) w1[i] = (short)tile[gq * 16 + 8 + i][d];
    ushort* dst = vT + (size_t)(d0 + d) * TSEQ + t0 + gq * 16;
    *(short8*)dst       = w0;
    *(short8*)(dst + 8) = w1;
}

// ---------------- GEMM BN=128 ----------------
template<int EPI>
__global__ __launch_bounds__(256) void gemm_kernel(
    const ushort* __restrict__ A, const ushort* __restrict__ Bt,
    const float* __restrict__ bias, const float* __restrict__ res,
    void* __restrict__ out, int M, int N, int K)
{
    __shared__ ushort As[2][128 * 32];
    __shared__ ushort Bs[2][128 * 32];
    int bm = blockIdx.x * 128, bn = blockIdx.y * 128;
    int tid = threadIdx.x;
    int wid = tid >> 6, lane = tid & 63;
    int wm = (wid >> 1) * 64, wn = (wid & 1) * 64;
    int lg = lane >> 4, lr = lane & 15;
    int srow = lane >> 2, scol = (lane & 3) * 8;
    f32x4 acc[4][4] = {};

    const ushort* ga0 = A  + (size_t)(bm + wid * 16 + srow) * K + scol;
    const ushort* ga1 = A  + (size_t)(bm + 64 + wid * 16 + srow) * K + scol;
    const ushort* gb0 = Bt + (size_t)(bn + wid * 16 + srow) * K + scol;
    const ushort* gb1 = Bt + (size_t)(bn + 64 + wid * 16 + srow) * K + scol;

    gl_lds16(ga0, &As[0][wid * 512]);
    gl_lds16(ga1, &As[0][2048 + wid * 512]);
    gl_lds16(gb0, &Bs[0][wid * 512]);
    gl_lds16(gb1, &Bs[0][2048 + wid * 512]);

    int nt = K >> 5;
    for (int t = 0; t < nt; t++) {
        int cur = t & 1;
        __syncthreads();
        if (t + 1 < nt) {
            int k0 = (t + 1) << 5;
            int nb = cur ^ 1;
            gl_lds16(ga0 + k0, &As[nb][wid * 512]);
            gl_lds16(ga1 + k0, &As[nb][2048 + wid * 512]);
            gl_lds16(gb0 + k0, &Bs[nb][wid * 512]);
            gl_lds16(gb1 + k0, &Bs[nb][2048 + wid * 512]);
        }
        short8 a[4], b[4];
        #pragma unroll
        for (int mi = 0; mi < 4; mi++) a[mi] = *(const short8*)&As[cur][(wm + mi * 16 + lr) * 32 + lg * 8];
        #pragma unroll
        for (int ni = 0; ni < 4; ni++) b[ni] = *(const short8*)&Bs[cur][(wn + ni * 16 + lr) * 32 + lg * 8];
        #pragma unroll
        for (int mi = 0; mi < 4; mi++)
            #pragma unroll
            for (int ni = 0; ni < 4; ni++)
                acc[mi][ni] = __builtin_amdgcn_mfma_f32_16x16x32_bf16(a[mi], b[ni], acc[mi][ni], 0, 0, 0);
    }

    #pragma unroll
    for (int mi = 0; mi < 4; mi++) {
        #pragma unroll
        for (int ni = 0; ni < 4; ni++) {
            int col = bn + wn + ni * 16 + lr;
            float bv = bias[col];
            #pragma unroll
            for (int r = 0; r < 4; r++) {
                int row = bm + wm + mi * 16 + lg * 4 + r;
                float v = acc[mi][ni][r] + bv;
                size_t idx = (size_t)row * N + col;
                if (EPI == 0) {
                    ((ushort*)out)[idx] = f2bf(v);
                } else if (EPI == 1) {
                    ((ushort*)out)[idx] = f2bf(gelu_fast(v));
                } else {
                    ((float*)out)[idx] = v + res[idx];
                }
            }
        }
    }
}

// ---------------- GEMM BN=64 (skinny-N: out-proj, FC2) ----------------
template<int EPI>
__global__ __launch_bounds__(256) void gemm_n64_kernel(
    const ushort* __restrict__ A, const ushort* __restrict__ Bt,
    const float* __restrict__ bias, const float* __restrict__ res,
    void* __restrict__ out, int M, int N, int K)
{
    __shared__ ushort As[2][128 * 32];
    __shared__ ushort Bs[2][64 * 32];
    int bm = blockIdx.x * 128, bn = blockIdx.y * 64;
    int tid = threadIdx.x;
    int wid = tid >> 6, lane = tid & 63;
    int wm = (wid >> 1) * 64, wn = (wid & 1) * 32;
    int lg = lane >> 4, lr = lane & 15;
    int srow = lane >> 2, scol = (lane & 3) * 8;
    f32x4 acc[4][2] = {};

    const ushort* ga0 = A  + (size_t)(bm + wid * 16 + srow) * K + scol;
    const ushort* ga1 = A  + (size_t)(bm + 64 + wid * 16 + srow) * K + scol;
    const ushort* gb0 = Bt + (size_t)(bn + wid * 16 + srow) * K + scol;

    gl_lds16(ga0, &As[0][wid * 512]);
    gl_lds16(ga1, &As[0][2048 + wid * 512]);
    gl_lds16(gb0, &Bs[0][wid * 512]);

    int nt = K >> 5;
    for (int t = 0; t < nt; t++) {
        int cur = t & 1;
        __syncthreads();
        if (t + 1 < nt) {
            int k0 = (t + 1) << 5;
            int nb = cur ^ 1;
            gl_lds16(ga0 + k0, &As[nb][wid * 512]);
            gl_lds16(ga1 + k0, &As[nb][2048 + wid * 512]);
            gl_lds16(gb0 + k0, &Bs[nb][wid * 512]);
        }
        short8 a[4], b[2];
        #pragma unroll
        for (int mi = 0; mi < 4; mi++) a[mi] = *(const short8*)&As[cur][(wm + mi * 16 + lr) * 32 + lg * 8];
        #pragma unroll
        for (int ni = 0; ni < 2; ni++) b[ni] = *(const short8*)&Bs[cur][(wn + ni * 16 + lr) * 32 + lg * 8];
        #pragma unroll
        for (int mi = 0; mi < 4; mi++)
            #pragma unroll
            for (int ni = 0; ni < 2; ni++)
                acc[mi][ni] = __builtin_amdgcn_mfma_f32_16x16x32_bf16(a[mi], b[ni], acc[mi][ni], 0, 0, 0);
    }

    #pragma unroll
    for (int mi = 0; mi < 4; mi++) {
        #pragma unroll
        for (int ni = 0; ni < 2; ni++) {
            int col = bn + wn + ni * 16 + lr;
            float bv = bias[col];
            #pragma unroll
            for (int r = 0; r < 4; r++) {
                int row = bm + wm + mi * 16 + lg * 4 + r;
                float v = acc[mi][ni][r] + bv;
                size_t idx = (size_t)row * N + col;
                if (EPI == 0) {
                    ((ushort*)out)[idx] = f2bf(v);
                } else if (EPI == 1) {
                    ((ushort*)out)[idx] = f2bf(gelu_fast(v));
                } else {
                    ((float*)out)[idx] = v + res[idx];
                }
            }
        }
    }
}

// ---------------- flash attention (32x32 MFMA, in-register P, split-K x4) ----------------
// 4 waves x 32 q-rows (QBLK=128), KVBLK=64, NT=16 tiles/split. No Q/P LDS:
// Q global->reg; swapped QK^T (32x32) leaves P-row lane-local up to a lane^32
// exchange -> v_permlane32_swap_b32 builds PV A-fragments entirely in registers.
// K/V staged via gl_lds (XOR-unit-swizzled source), double-buffered. LDS = 32KB.
// Static-max softmax; lsum via ones-MFMA.
__global__ __launch_bounds__(256) void attn_kernel(
    const ushort* __restrict__ qkv, const ushort* __restrict__ vT,
    ushort* __restrict__ Opart, float* __restrict__ ml)
{
    int head = blockIdx.y;
    int qblk = blockIdx.x;
    int split = blockIdx.z;
    __shared__ ushort smem[16384];            // Ks dbuf [2][4096] + Vt dbuf [2][4096]
    int tid = threadIdx.x, w = tid >> 6, lane = tid & 63;
    int l31 = lane & 31, h_ = lane >> 5, x7 = lane & 7;
    const float C1 = 0.18033688011112042f;    // 0.125 * log2(e)
    const float KC = 12.0f * C1;

    // staging geometry: row (tid>>3)+32s, unit (tid&7)^((tid>>3)&7); dest tid*8+s*2048
    int srow7 = (tid >> 3) & 7;
    int sunit = (tid & 7) ^ srow7;
    const ushort* kg = qkv + (size_t)(split * 1024 + (tid >> 3)) * 2304 + DMODEL + head * HDIM + sunit * 8;
    const ushort* vgp = vT + (size_t)(head * HDIM + (tid >> 3)) * TSEQ + split * 1024 + sunit * 8;

    gl_lds16(kg,              &smem[tid * 8]);
    gl_lds16(kg + 32 * 2304,  &smem[tid * 8 + 2048]);
    gl_lds16(vgp,             &smem[8192 + tid * 8]);
    gl_lds16(vgp + 32 * TSEQ, &smem[8192 + tid * 8 + 2048]);
    kg += 64 * 2304;
    vgp += 64;

    // Q -> registers: lane holds Q[q = qblk*128 + w*32 + l31][d = 16j + 8h + 0..7]
    short8 qreg[4];
    {
        const ushort* qsrc = qkv + (size_t)(qblk * 128 + w * 32 + l31) * 2304 + head * HDIM + 8 * h_;
        #pragma unroll
        for (int j = 0; j < 4; j++) qreg[j] = *(const short8*)(qsrc + 16 * j);
    }

    short8 vone;
    #pragma unroll
    for (int i = 0; i < 8; i++) vone[i] = (short)0x3F80;

    f32x16 o0 = {}, o1 = {}, olsum = {};
    const int NT = 16;

    for (int kt = 0; kt < NT; kt++) {
        int cur = kt & 1, nb = cur ^ 1;
        __syncthreads();                      // buf[cur] ready (drains vmcnt)
        if (kt + 1 < NT) {
            gl_lds16(kg,              &smem[nb * 4096 + tid * 8]);
            gl_lds16(kg + 32 * 2304,  &smem[nb * 4096 + tid * 8 + 2048]);
            gl_lds16(vgp,             &smem[8192 + nb * 4096 + tid * 8]);
            gl_lds16(vgp + 32 * TSEQ, &smem[8192 + nb * 4096 + tid * 8 + 2048]);
            kg += 64 * 2304;
            vgp += 64;
        }
        const ushort* kb_ = &smem[cur * 4096];
        const ushort* vb_ = &smem[8192 + cur * 4096];

        // ST = K Q^T : st[kb] holds P^T[k = 32kb + (r&3)+8(r>>2)+4h][q = l31]
        f32x16 st0 = {}, st1 = {};
        __builtin_amdgcn_s_setprio(1);
        #pragma unroll
        for (int j = 0; j < 4; j++) {
            int u = ((2 * j + h_) ^ x7) * 8;
            short8 k0 = *(const short8*)&kb_[l31 * 64 + u];
            short8 k1 = *(const short8*)&kb_[(32 + l31) * 64 + u];
            st0 = __builtin_amdgcn_mfma_f32_32x32x16_bf16(k0, qreg[j], st0, 0, 0, 0);
            st1 = __builtin_amdgcn_mfma_f32_32x32x16_bf16(k1, qreg[j], st1, 0, 0, 0);
        }
        __builtin_amdgcn_s_setprio(0);

        // static-max exp + pack: W[j][p] = bf16-pair P[q][k=8j+4h+2p .. +1]
        uint W[8][2];
        #pragma unroll
        for (int g = 0; g < 4; g++) {
            float a0 = exp2f(st0[4 * g + 0] * C1 - KC);
            float a1 = exp2f(st0[4 * g + 1] * C1 - KC);
            float a2 = exp2f(st0[4 * g + 2] * C1 - KC);
            float a3 = exp2f(st0[4 * g + 3] * C1 - KC);
            asm("v_cvt_pk_bf16_f32 %0, %1, %2" : "=v"(W[g][0]) : "v"(a0), "v"(a1));
            asm("v_cvt_pk_bf16_f32 %0, %1, %2" : "=v"(W[g][1]) : "v"(a2), "v"(a3));
            float b0 = exp2f(st1[4 * g + 0] * C1 - KC);
            float b1 = exp2f(st1[4 * g + 1] * C1 - KC);
            float b2 = exp2f(st1[4 * g + 2] * C1 - KC);
            float b3 = exp2f(st1[4 * g + 3] * C1 - KC);
            asm("v_cvt_pk_bf16_f32 %0, %1, %2" : "=v"(W[4 + g][0]) : "v"(b0), "v"(b1));
            asm("v_cvt_pk_bf16_f32 %0, %1, %2" : "=v"(W[4 + g][1]) : "v"(b2), "v"(b3));
        }

        // in-register transpose: A-frag dword (m,t) = W[2m + t>>1-side] via lane^32 swap
        uint R[4][4];
        #pragma unroll
        for (int m = 0; m < 4; m++)
            #pragma unroll
            for (int pp = 0; pp < 2; pp++) {
                uint a = W[2 * m][pp], b = W[2 * m + 1][pp];
                asm("v_permlane32_swap_b32 %0, %1" : "+v"(a), "+v"(b));
                R[m][pp]     = a;      // k-pair 16m + 8h + 2pp
                R[m][pp + 2] = b;      // k-pair 16m + 8h + 2pp + 4
            }

        // O += P V ; lsum += P * ones
        __builtin_amdgcn_s_setprio(1);
        #pragma unroll
        for (int m = 0; m < 4; m++) {
            union { u32x4 u; short8 s; } cv;
            cv.u = (u32x4){R[m][0], R[m][1], R[m][2], R[m][3]};
            short8 af = cv.s;
            olsum = __builtin_amdgcn_mfma_f32_32x32x16_bf16(af, vone, olsum, 0, 0, 0);
            int u = ((2 * m + h_) ^ x7) * 8;
            short8 v0 = *(const short8*)&vb_[l31 * 64 + u];
            short8 v1 = *(const short8*)&vb_[(32 + l31) * 64 + u];
            o0 = __builtin_amdgcn_mfma_f32_32x32x16_bf16(af, v0, o0, 0, 0, 0);
            o1 = __builtin_amdgcn_mfma_f32_32x32x16_bf16(af, v1, o1, 0, 0, 0);
        }
        __builtin_amdgcn_s_setprio(0);
    }

    // epilogue: o[n] lane holds O[q_local=(r&3)+8(r>>2)+4h][d=32n+l31]
    int qbase = qblk * 128 + w * 32;
    if (l31 == 0) {
        #pragma unroll
        for (int r = 0; r < 16; r++) {
            int ql = (r & 3) + 8 * (r >> 2) + 4 * h_;
            ml[((size_t)split * NHEADS + head) * TSEQ + qbase + ql] = olsum[r];
        }
    }
    #pragma unroll
    for (int r = 0; r < 16; r++) {
        int ql = (r & 3) + 8 * (r >> 2) + 4 * h_;
        size_t base = ((size_t)split * TSEQ + qbase + ql) * DMODEL + head * HDIM;
        Opart[base + l31]      = f2bf(o0[r]);
        Opart[base + 32 + l31] = f2bf(o1[r]);
    }
}

// ---------------- combine 4 split partials -> attn bf16 ----------------
__global__ __launch_bounds__(256) void attn_combine_kernel(
    const ushort* __restrict__ Opart, const float* __restrict__ ml,
    ushort* __restrict__ attnb)
{
    int gid = blockIdx.x * 256 + threadIdx.x;
    int q = gid / 192;
    int c = (gid - q * 192) * 4;
    int hh = c >> 6;
    float denom = 0.f;
    float a0 = 0.f, a1 = 0.f, a2 = 0.f, a3 = 0.f;
    #pragma unroll
    for (int s = 0; s < 4; s++) {
        denom += ml[((size_t)s * NHEADS + hh) * TSEQ + q];
        uint2 ov = *(const uint2*)&Opart[((size_t)s * TSEQ + q) * DMODEL + c];
        a0 += asf(ov.x << 16);
        a1 += asf(ov.x & 0xFFFF0000u);
        a2 += asf(ov.y << 16);
        a3 += asf(ov.y & 0xFFFF0000u);
    }
    float rd = 1.f / denom;
    uint2 stv;
    stv.x = (uint)f2bf(a0 * rd) | ((uint)f2bf(a1 * rd) << 16);
    stv.y = (uint)f2bf(a2 * rd) | ((uint)f2bf(a3 * rd) << 16);
    *(uint2*)&attnb[(size_t)q * DMODEL + c] = stv;
}

// ---------------- host launch ----------------
extern "C" void kernel_launch(void* const* d_in, const int* in_sizes, int n_in,
                              void* d_out, int out_size, void* d_ws, size_t ws_size,
                              hipStream_t stream)
{
    const float* x      = (const float*)d_in[0];
    const float* ln1_g  = (const float*)d_in[1];
    const float* ln1_b  = (const float*)d_in[2];
    const float* ln2_g  = (const float*)d_in[3];
    const float* ln2_b  = (const float*)d_in[4];
    const float* qkv_w  = (const float*)d_in[5];
    const float* qkv_b  = (const float*)d_in[6];
    const float* out_w  = (const float*)d_in[7];
    const float* out_b  = (const float*)d_in[8];
    const float* fc1_w  = (const float*)d_in[9];
    const float* fc1_b  = (const float*)d_in[10];
    const float* fc2_w  = (const float*)d_in[11];
    const float* fc2_b  = (const float*)d_in[12];
    (void)in_sizes; (void)n_in; (void)out_size; (void)ws_size;

    char* p = (char*)d_ws;
    ushort* qkvb  = (ushort*)p;                 p += (size_t)TSEQ * DFF * 2;          // also gelu-out
    ushort* hb    = (ushort*)p;                 p += (size_t)TSEQ * DMODEL * 2;
    ushort* attnb = (ushort*)p;                 p += (size_t)TSEQ * DMODEL * 2;
    float*  x2    = (float*)p;                  p += (size_t)TSEQ * DMODEL * 4;
    ushort* qkv_wT = (ushort*)p;                p += (size_t)(3 * DMODEL) * DMODEL * 2;
    ushort* out_wT = (ushort*)p;                p += (size_t)DMODEL * DMODEL * 2;
    ushort* fc1_wT = (ushort*)p;                p += (size_t)DFF * DMODEL * 2;
    ushort* fc2_wT = (ushort*)p;                p += (size_t)DMODEL * DFF * 2;
    ushort* Opart  = (ushort*)p;                p += (size_t)4 * TSEQ * DMODEL * 2;
    float*  mlbuf  = (float*)p;                 p += (size_t)4 * NHEADS * TSEQ * 4;
    ushort* vTb    = (ushort*)p;                p += (size_t)DMODEL * TSEQ * 2;
    ushort* gb = qkvb;

    transpose_cast_kernel<<<dim3(DMODEL / 32, 3 * DMODEL / 32), 256, 0, stream>>>(qkv_w, qkv_wT, DMODEL, 3 * DMODEL);
    transpose_cast_kernel<<<dim3(DMODEL / 32, DMODEL / 32), 256, 0, stream>>>(out_w, out_wT, DMODEL, DMODEL);
    transpose_cast_kernel<<<dim3(DMODEL / 32, DFF / 32), 256, 0, stream>>>(fc1_w, fc1_wT, DMODEL, DFF);
    transpose_cast_kernel<<<dim3(DFF / 32, DMODEL / 32), 256, 0, stream>>>(fc2_w, fc2_wT, DFF, DMODEL);

    ln_half_kernel<<<TSEQ, 256, 0, stream>>>(x, ln1_g, ln1_b, hb);
    gemm_kernel<0><<<dim3(TSEQ / 128, 3 * DMODEL / 128), 256, 0, stream>>>(
        hb, qkv_wT, qkv_b, nullptr, qkvb, TSEQ, 3 * DMODEL, DMODEL);
    vtrans_kernel<<<dim3(TSEQ / 64, DMODEL / 64), 256, 0, stream>>>(qkvb, vTb);
    attn_kernel<<<dim3(TSEQ / 128, NHEADS, 4), 256, 0, stream>>>(qkvb, vTb, Opart, mlbuf);
    attn_combine_kernel<<<(TSEQ * DMODEL / 4) / 256, 256, 0, stream>>>(Opart, mlbuf, attnb);
    gemm_n64_kernel<2><<<dim3(TSEQ / 128, DMODEL / 64), 256, 0, stream>>>(
        attnb, out_wT, out_b, x, x2, TSEQ, DMODEL, DMODEL);
    ln_half_kernel<<<TSEQ, 256, 0, stream>>>(x2, ln2_g, ln2_b, hb);
    gemm_kernel<1><<<dim3(TSEQ / 128, DFF / 128), 256, 0, stream>>>(
        hb, fc1_wT, fc1_b, nullptr, gb, TSEQ, DFF, DMODEL);
    gemm_n64_kernel<2><<<dim3(TSEQ / 128, DMODEL / 64), 256, 0, stream>>>(
        gb, fc2_wT, fc2_b, x2, (float*)d_out, TSEQ, DMODEL, DFF);
}

// Round 14
// 225.296 us; speedup vs baseline: 1.0485x; 1.0485x over previous
//
#include <hip/hip_runtime.h>
#include <hip/hip_bf16.h>
#include <math.h>

#define TSEQ 4096
#define DMODEL 768
#define DFF 3072
#define NHEADS 12
#define HDIM 64

typedef __attribute__((ext_vector_type(8))) short short8;
typedef __attribute__((ext_vector_type(4))) float f32x4;
typedef unsigned short ushort;
typedef unsigned int uint;

typedef __attribute__((address_space(1))) ushort as1_ushort;
typedef __attribute__((address_space(3))) ushort as3_ushort;

__device__ __forceinline__ void gl_lds16(const ushort* g, const ushort* l) {
    __builtin_amdgcn_global_load_lds((as1_ushort*)(uintptr_t)g,
                                     (as3_ushort*)(uint)(uintptr_t)l, 16, 0, 0);
}

__device__ __forceinline__ ushort f2bf(float f) {
    union { float f; unsigned i; } c; c.f = f;
    unsigned x = c.i;
    unsigned r = x + 0x7FFFu + ((x >> 16) & 1u);
    return (ushort)(r >> 16);
}
__device__ __forceinline__ float asf(uint u) {
    union { unsigned i; float f; } c; c.i = u; return c.f;
}
// tanh-form GELU
__device__ __forceinline__ float gelu_fast(float v) {
    float y = v * (0.7978845608f + 0.03567740814f * v * v);
    float u = exp2f(y * -2.8853900817779268f);
    float r;
    asm("v_rcp_f32 %0, %1" : "=v"(r) : "v"(1.f + u));
    return v * r;
}

// ---------------- LayerNorm * 0.5 -> bf16 ----------------
__global__ __launch_bounds__(256) void ln_half_kernel(
    const float* __restrict__ x, const float* __restrict__ g,
    const float* __restrict__ b, ushort* __restrict__ out)
{
    int row = blockIdx.x;
    const float* xr = x + (size_t)row * DMODEL;
    float v[3];
    float s = 0.f, s2 = 0.f;
    #pragma unroll
    for (int i = 0; i < 3; i++) {
        v[i] = xr[threadIdx.x + 256 * i];
        s += v[i]; s2 += v[i] * v[i];
    }
    #pragma unroll
    for (int m = 1; m < 64; m <<= 1) { s += __shfl_xor(s, m, 64); s2 += __shfl_xor(s2, m, 64); }
    __shared__ float ss[4], ss2[4];
    int wid = threadIdx.x >> 6;
    if ((threadIdx.x & 63) == 0) { ss[wid] = s; ss2[wid] = s2; }
    __syncthreads();
    s = ss[0] + ss[1] + ss[2] + ss[3];
    s2 = ss2[0] + ss2[1] + ss2[2] + ss2[3];
    float mu = s * (1.f / DMODEL);
    float var = s2 * (1.f / DMODEL) - mu * mu;
    float rs = rsqrtf(var + 1e-5f);
    #pragma unroll
    for (int i = 0; i < 3; i++) {
        int c = threadIdx.x + 256 * i;
        float h = (v[i] - mu) * rs * g[c] + b[c];
        out[(size_t)row * DMODEL + c] = f2bf(h * 0.5f);
    }
}

// ---------------- transpose + cast: in [K,N] f32 -> out [N,K] bf16 ----------------
__global__ __launch_bounds__(256) void transpose_cast_kernel(
    const float* __restrict__ in, ushort* __restrict__ out, int K, int N)
{
    __shared__ float tile[32][33];
    int k0 = blockIdx.x * 32, n0 = blockIdx.y * 32;
    int c = threadIdx.x & 31, r0 = threadIdx.x >> 5;
    #pragma unroll
    for (int i = 0; i < 4; i++) {
        int r = r0 + i * 8;
        tile[r][c] = in[(size_t)(k0 + r) * N + n0 + c];
    }
    __syncthreads();
    #pragma unroll
    for (int i = 0; i < 4; i++) {
        int r = r0 + i * 8;
        out[(size_t)(n0 + r) * K + k0 + c] = f2bf(tile[c][r]);
    }
}

// ---------------- V transpose: qkvb [T,2304] (V cols 1536..2303) -> vT [768][T] bf16 ----------------
__global__ __launch_bounds__(256) void vtrans_kernel(
    const ushort* __restrict__ qkvb, ushort* __restrict__ vT)
{
    __shared__ ushort tile[64][72];
    int t0 = blockIdx.x * 64, d0 = blockIdx.y * 64;
    int tid = threadIdx.x;
    int r = tid >> 2, c = (tid & 3) * 16;
    const ushort* src = qkvb + (size_t)(t0 + r) * 2304 + 1536 + d0 + c;
    *(short8*)&tile[r][c]     = *(const short8*)src;
    *(short8*)&tile[r][c + 8] = *(const short8*)(src + 8);
    __syncthreads();
    int d = tid & 63, gq = tid >> 6;
    short8 w0, w1;
    #pragma unroll
    for (int i = 0; i < 8; i++) w0[i] = (short)tile[gq * 16 + i][d];
    #pragma unroll
    for (int i = 0; i < 8; i++) w1[i] = (short)tile[gq * 16 + 8 + i][d];
    ushort* dst = vT + (size_t)(d0 + d) * TSEQ + t0 + gq * 16;
    *(short8*)dst       = w0;
    *(short8*)(dst + 8) = w1;
}

// ---------------- GEMM BN=128 ----------------
template<int EPI>
__global__ __launch_bounds__(256) void gemm_kernel(
    const ushort* __restrict__ A, const ushort* __restrict__ Bt,
    const float* __restrict__ bias, const float* __restrict__ res,
    void* __restrict__ out, int M, int N, int K)
{
    __shared__ ushort As[2][128 * 32];
    __shared__ ushort Bs[2][128 * 32];
    int bm = blockIdx.x * 128, bn = blockIdx.y * 128;
    int tid = threadIdx.x;
    int wid = tid >> 6, lane = tid & 63;
    int wm = (wid >> 1) * 64, wn = (wid & 1) * 64;
    int lg = lane >> 4, lr = lane & 15;
    int srow = lane >> 2, scol = (lane & 3) * 8;
    f32x4 acc[4][4] = {};

    const ushort* ga0 = A  + (size_t)(bm + wid * 16 + srow) * K + scol;
    const ushort* ga1 = A  + (size_t)(bm + 64 + wid * 16 + srow) * K + scol;
    const ushort* gb0 = Bt + (size_t)(bn + wid * 16 + srow) * K + scol;
    const ushort* gb1 = Bt + (size_t)(bn + 64 + wid * 16 + srow) * K + scol;

    gl_lds16(ga0, &As[0][wid * 512]);
    gl_lds16(ga1, &As[0][2048 + wid * 512]);
    gl_lds16(gb0, &Bs[0][wid * 512]);
    gl_lds16(gb1, &Bs[0][2048 + wid * 512]);

    int nt = K >> 5;
    for (int t = 0; t < nt; t++) {
        int cur = t & 1;
        __syncthreads();
        if (t + 1 < nt) {
            int k0 = (t + 1) << 5;
            int nb = cur ^ 1;
            gl_lds16(ga0 + k0, &As[nb][wid * 512]);
            gl_lds16(ga1 + k0, &As[nb][2048 + wid * 512]);
            gl_lds16(gb0 + k0, &Bs[nb][wid * 512]);
            gl_lds16(gb1 + k0, &Bs[nb][2048 + wid * 512]);
        }
        short8 a[4], b[4];
        #pragma unroll
        for (int mi = 0; mi < 4; mi++) a[mi] = *(const short8*)&As[cur][(wm + mi * 16 + lr) * 32 + lg * 8];
        #pragma unroll
        for (int ni = 0; ni < 4; ni++) b[ni] = *(const short8*)&Bs[cur][(wn + ni * 16 + lr) * 32 + lg * 8];
        #pragma unroll
        for (int mi = 0; mi < 4; mi++)
            #pragma unroll
            for (int ni = 0; ni < 4; ni++)
                acc[mi][ni] = __builtin_amdgcn_mfma_f32_16x16x32_bf16(a[mi], b[ni], acc[mi][ni], 0, 0, 0);
    }

    #pragma unroll
    for (int mi = 0; mi < 4; mi++) {
        #pragma unroll
        for (int ni = 0; ni < 4; ni++) {
            int col = bn + wn + ni * 16 + lr;
            float bv = bias[col];
            #pragma unroll
            for (int r = 0; r < 4; r++) {
                int row = bm + wm + mi * 16 + lg * 4 + r;
                float v = acc[mi][ni][r] + bv;
                size_t idx = (size_t)row * N + col;
                if (EPI == 0) {
                    ((ushort*)out)[idx] = f2bf(v);
                } else if (EPI == 1) {
                    ((ushort*)out)[idx] = f2bf(gelu_fast(v));
                } else {
                    ((float*)out)[idx] = v + res[idx];
                }
            }
        }
    }
}

// ---------------- GEMM BN=64 (skinny-N: out-proj, FC2) ----------------
template<int EPI>
__global__ __launch_bounds__(256) void gemm_n64_kernel(
    const ushort* __restrict__ A, const ushort* __restrict__ Bt,
    const float* __restrict__ bias, const float* __restrict__ res,
    void* __restrict__ out, int M, int N, int K)
{
    __shared__ ushort As[2][128 * 32];
    __shared__ ushort Bs[2][64 * 32];
    int bm = blockIdx.x * 128, bn = blockIdx.y * 64;
    int tid = threadIdx.x;
    int wid = tid >> 6, lane = tid & 63;
    int wm = (wid >> 1) * 64, wn = (wid & 1) * 32;
    int lg = lane >> 4, lr = lane & 15;
    int srow = lane >> 2, scol = (lane & 3) * 8;
    f32x4 acc[4][2] = {};

    const ushort* ga0 = A  + (size_t)(bm + wid * 16 + srow) * K + scol;
    const ushort* ga1 = A  + (size_t)(bm + 64 + wid * 16 + srow) * K + scol;
    const ushort* gb0 = Bt + (size_t)(bn + wid * 16 + srow) * K + scol;

    gl_lds16(ga0, &As[0][wid * 512]);
    gl_lds16(ga1, &As[0][2048 + wid * 512]);
    gl_lds16(gb0, &Bs[0][wid * 512]);

    int nt = K >> 5;
    for (int t = 0; t < nt; t++) {
        int cur = t & 1;
        __syncthreads();
        if (t + 1 < nt) {
            int k0 = (t + 1) << 5;
            int nb = cur ^ 1;
            gl_lds16(ga0 + k0, &As[nb][wid * 512]);
            gl_lds16(ga1 + k0, &As[nb][2048 + wid * 512]);
            gl_lds16(gb0 + k0, &Bs[nb][wid * 512]);
        }
        short8 a[4], b[2];
        #pragma unroll
        for (int mi = 0; mi < 4; mi++) a[mi] = *(const short8*)&As[cur][(wm + mi * 16 + lr) * 32 + lg * 8];
        #pragma unroll
        for (int ni = 0; ni < 2; ni++) b[ni] = *(const short8*)&Bs[cur][(wn + ni * 16 + lr) * 32 + lg * 8];
        #pragma unroll
        for (int mi = 0; mi < 4; mi++)
            #pragma unroll
            for (int ni = 0; ni < 2; ni++)
                acc[mi][ni] = __builtin_amdgcn_mfma_f32_16x16x32_bf16(a[mi], b[ni], acc[mi][ni], 0, 0, 0);
    }

    #pragma unroll
    for (int mi = 0; mi < 4; mi++) {
        #pragma unroll
        for (int ni = 0; ni < 2; ni++) {
            int col = bn + wn + ni * 16 + lr;
            float bv = bias[col];
            #pragma unroll
            for (int r = 0; r < 4; r++) {
                int row = bm + wm + mi * 16 + lg * 4 + r;
                float v = acc[mi][ni][r] + bv;
                size_t idx = (size_t)row * N + col;
                if (EPI == 0) {
                    ((ushort*)out)[idx] = f2bf(v);
                } else if (EPI == 1) {
                    ((ushort*)out)[idx] = f2bf(gelu_fast(v));
                } else {
                    ((float*)out)[idx] = v + res[idx];
                }
            }
        }
    }
}

// ---------------- flash attention (split-K x8, QBLK=256, counted-vmcnt 3-buffer) ----------------
// 8 waves x 32 q-rows, NT=8 tiles/block. K/V triple-buffered via gl_lds; per tile:
// issue next-tile loads FIRST, then s_waitcnt vmcnt(2) + raw s_barrier (T4: loads
// stay in flight across the barrier; never drained to 0 in the loop body).
// Q staged through LDS (dest-XOR swizzle), PV split into two k-32 halves on a
// [256][40] P scratch. Static-max softmax, ones-MFMA lsum, setprio on MFMA.
__global__ __launch_bounds__(512) void attn_kernel(
    const ushort* __restrict__ qkv, const ushort* __restrict__ vT,
    ushort* __restrict__ Opart, float* __restrict__ ml)
{
    int h = blockIdx.y;
    int qblk = blockIdx.x;
    int split = blockIdx.z;
    // Ks[3][4096] @ 0, Vt[3][4096] @ 12288, Ps[256*40] @ 24576  (total 69632 B)
    __shared__ ushort smem[24576 + 256 * 40];
    ushort* Ps = smem + 24576;
    int tid = threadIdx.x, wid = tid >> 6, lane = tid & 63;
    int lg = lane >> 4, lr = lane & 15;
    const float C1 = 0.18033688011112042f;   // 0.125 * log2(e)
    const float KC = 12.0f * C1;
    int x7 = lr & 7;

    { // stage Q: dest-XOR swizzled LDS (bank-spread), linear global source
        int row = tid >> 1;
        int u0 = (tid & 1) * 4;
        int r7 = row & 7;
        const ushort* src = qkv + (size_t)(qblk * 256 + row) * 2304 + h * HDIM;
        #pragma unroll
        for (int i = 0; i < 4; i++) {
            int u = u0 + i;
            *(short8*)&smem[row * 64 + ((u ^ r7) * 8)] = *(const short8*)(src + (size_t)(u * 8));
        }
    }
    int q0row = (wid * 32 + lr) * 64;
    int q1row = q0row + 16 * 64;
    short8 qa0 = *(const short8*)&smem[q0row + (lg ^ x7) * 8];
    short8 qa1 = *(const short8*)&smem[q0row + ((4 + lg) ^ x7) * 8];
    short8 qb0 = *(const short8*)&smem[q1row + (lg ^ x7) * 8];
    short8 qb1 = *(const short8*)&smem[q1row + ((4 + lg) ^ x7) * 8];
    __syncthreads();    // everyone done reading Q before K/V overwrite

    short8 vone;
    #pragma unroll
    for (int i = 0; i < 8; i++) vone[i] = (short)0x3F80;

    // staging geometry (dest linear [64][64], source 16B-unit XOR swizzle by row&7)
    int krow = tid >> 3;
    int kunit = (tid & 7) ^ (krow & 7);
    const ushort* kg = qkv + (size_t)(split * 512 + krow) * 2304 + DMODEL + h * HDIM + kunit * 8;
    const ushort* vgp = vT + (size_t)(h * HDIM + krow) * TSEQ + split * 512 + kunit * 8;

    gl_lds16(kg, &smem[tid * 8]);              // K buf0
    gl_lds16(vgp, &smem[12288 + tid * 8]);     // V buf0
    kg += 64 * 2304;
    vgp += 64;

    f32x4 o0[4] = {}, o1[4] = {};
    f32x4 s0sum = {}, s1sum = {};
    const int NT = 8;                          // tiles per split (4096/64/8)
    int prow0 = (wid * 32 + lr) * 40;
    int prow1 = prow0 + 16 * 40;

    int cur = 0;
    for (int kt = 0; kt < NT; kt++) {
        int nb = (cur == 2) ? 0 : cur + 1;
        if (kt + 1 < NT) {
            // issue next tile's loads FIRST (into buf[(kt+1)%3] = buf[(kt-2)%3],
            // safe: all waves passed barrier(kt-1) => finished compute(kt-2))
            gl_lds16(kg, &smem[nb * 4096 + tid * 8]);
            gl_lds16(vgp, &smem[12288 + nb * 4096 + tid * 8]);
            kg += 64 * 2304;
            vgp += 64;
            asm volatile("s_waitcnt vmcnt(2)" ::: "memory");   // tile kt's loads done
        } else {
            asm volatile("s_waitcnt vmcnt(0)" ::: "memory");
        }
        __builtin_amdgcn_s_barrier();
        const ushort* kb = &smem[cur * 4096];
        const ushort* vb = &smem[12288 + cur * 4096];

        // S^T = K Q^T for both q-subsets (K-frags read once)
        f32x4 st0[4] = {}, st1[4] = {};
        __builtin_amdgcn_s_setprio(1);
        #pragma unroll
        for (int ki = 0; ki < 4; ki++) {
            const ushort* kr = &kb[(ki * 16 + lr) * 64];
            short8 k0 = *(const short8*)&kr[(lg ^ x7) * 8];
            short8 k1 = *(const short8*)&kr[((4 + lg) ^ x7) * 8];
            st0[ki] = __builtin_amdgcn_mfma_f32_16x16x32_bf16(k0, qa0, st0[ki], 0, 0, 0);
            st0[ki] = __builtin_amdgcn_mfma_f32_16x16x32_bf16(k1, qa1, st0[ki], 0, 0, 0);
            st1[ki] = __builtin_amdgcn_mfma_f32_16x16x32_bf16(k0, qb0, st1[ki], 0, 0, 0);
            st1[ki] = __builtin_amdgcn_mfma_f32_16x16x32_bf16(k1, qb1, st1[ki], 0, 0, 0);
        }
        __builtin_amdgcn_s_setprio(0);

        // static-max exp + pack into dword pairs
        uint2 c0[4], c1[4];
        #pragma unroll
        for (int ki = 0; ki < 4; ki++) {
            #pragma unroll
            for (int r = 0; r < 4; r++) st0[ki][r] = exp2f(st0[ki][r] * C1 - KC);
            asm("v_cvt_pk_bf16_f32 %0, %1, %2" : "=v"(c0[ki].x) : "v"(st0[ki][0]), "v"(st0[ki][1]));
            asm("v_cvt_pk_bf16_f32 %0, %1, %2" : "=v"(c0[ki].y) : "v"(st0[ki][2]), "v"(st0[ki][3]));
        }
        #pragma unroll
        for (int ki = 0; ki < 4; ki++) {
            #pragma unroll
            for (int r = 0; r < 4; r++) st1[ki][r] = exp2f(st1[ki][r] * C1 - KC);
            asm("v_cvt_pk_bf16_f32 %0, %1, %2" : "=v"(c1[ki].x) : "v"(st1[ki][0]), "v"(st1[ki][1]));
            asm("v_cvt_pk_bf16_f32 %0, %1, %2" : "=v"(c1[ki].y) : "v"(st1[ki][2]), "v"(st1[ki][3]));
        }

        // ---- half 0: k in [0,32) ----
        *(uint2*)&Ps[prow0 + lg * 4]      = c0[0];
        *(uint2*)&Ps[prow0 + 16 + lg * 4] = c0[1];
        *(uint2*)&Ps[prow1 + lg * 4]      = c1[0];
        *(uint2*)&Ps[prow1 + 16 + lg * 4] = c1[1];
        {
            short8 pa00 = *(const short8*)&Ps[prow0 + lg * 8];
            short8 pa10 = *(const short8*)&Ps[prow1 + lg * 8];
            __builtin_amdgcn_s_setprio(1);
            s0sum = __builtin_amdgcn_mfma_f32_16x16x32_bf16(pa00, vone, s0sum, 0, 0, 0);
            s1sum = __builtin_amdgcn_mfma_f32_16x16x32_bf16(pa10, vone, s1sum, 0, 0, 0);
            #pragma unroll
            for (int ni = 0; ni < 4; ni++) {
                short8 b0 = *(const short8*)&vb[(ni * 16 + lr) * 64 + (lg ^ x7) * 8];
                o0[ni] = __builtin_amdgcn_mfma_f32_16x16x32_bf16(pa00, b0, o0[ni], 0, 0, 0);
                o1[ni] = __builtin_amdgcn_mfma_f32_16x16x32_bf16(pa10, b0, o1[ni], 0, 0, 0);
            }
            __builtin_amdgcn_s_setprio(0);
        }
        // ---- half 1: k in [32,64) (reuses same P scratch cols) ----
        *(uint2*)&Ps[prow0 + lg * 4]      = c0[2];
        *(uint2*)&Ps[prow0 + 16 + lg * 4] = c0[3];
        *(uint2*)&Ps[prow1 + lg * 4]      = c1[2];
        *(uint2*)&Ps[prow1 + 16 + lg * 4] = c1[3];
        {
            short8 pa01 = *(const short8*)&Ps[prow0 + lg * 8];
            short8 pa11 = *(const short8*)&Ps[prow1 + lg * 8];
            __builtin_amdgcn_s_setprio(1);
            s0sum = __builtin_amdgcn_mfma_f32_16x16x32_bf16(pa01, vone, s0sum, 0, 0, 0);
            s1sum = __builtin_amdgcn_mfma_f32_16x16x32_bf16(pa11, vone, s1sum, 0, 0, 0);
            #pragma unroll
            for (int ni = 0; ni < 4; ni++) {
                short8 b1 = *(const short8*)&vb[(ni * 16 + lr) * 64 + ((4 + lg) ^ x7) * 8];
                o0[ni] = __builtin_amdgcn_mfma_f32_16x16x32_bf16(pa01, b1, o0[ni], 0, 0, 0);
                o1[ni] = __builtin_amdgcn_mfma_f32_16x16x32_bf16(pa11, b1, o1[ni], 0, 0, 0);
            }
            __builtin_amdgcn_s_setprio(0);
        }
        cur = nb;
    }

    // epilogue
    if (lr == 0) {
        #pragma unroll
        for (int r = 0; r < 4; r++) {
            int q0 = qblk * 256 + wid * 32 + lg * 4 + r;
            ml[((size_t)split * NHEADS + h) * TSEQ + q0]      = s0sum[r];
            ml[((size_t)split * NHEADS + h) * TSEQ + q0 + 16] = s1sum[r];
        }
    }
    #pragma unroll
    for (int ni = 0; ni < 4; ni++)
        #pragma unroll
        for (int r = 0; r < 4; r++) {
            int q0 = qblk * 256 + wid * 32 + lg * 4 + r;
            int dcol = ni * 16 + lr;
            Opart[((size_t)split * TSEQ + q0) * DMODEL + h * HDIM + dcol]      = f2bf(o0[ni][r]);
            Opart[((size_t)split * TSEQ + q0 + 16) * DMODEL + h * HDIM + dcol] = f2bf(o1[ni][r]);
        }
}

// ---------------- combine 8 split partials -> attn bf16 ----------------
__global__ __launch_bounds__(256) void attn_combine_kernel(
    const ushort* __restrict__ Opart, const float* __restrict__ ml,
    ushort* __restrict__ attnb)
{
    int gid = blockIdx.x * 256 + threadIdx.x;
    int q = gid / 192;
    int c = (gid - q * 192) * 4;
    int hh = c >> 6;
    float denom = 0.f;
    float a0 = 0.f, a1 = 0.f, a2 = 0.f, a3 = 0.f;
    #pragma unroll
    for (int s = 0; s < 8; s++) {
        denom += ml[((size_t)s * NHEADS + hh) * TSEQ + q];
        uint2 ov = *(const uint2*)&Opart[((size_t)s * TSEQ + q) * DMODEL + c];
        a0 += asf(ov.x << 16);
        a1 += asf(ov.x & 0xFFFF0000u);
        a2 += asf(ov.y << 16);
        a3 += asf(ov.y & 0xFFFF0000u);
    }
    float rd = 1.f / denom;
    uint2 stv;
    stv.x = (uint)f2bf(a0 * rd) | ((uint)f2bf(a1 * rd) << 16);
    stv.y = (uint)f2bf(a2 * rd) | ((uint)f2bf(a3 * rd) << 16);
    *(uint2*)&attnb[(size_t)q * DMODEL + c] = stv;
}

// ---------------- host launch ----------------
extern "C" void kernel_launch(void* const* d_in, const int* in_sizes, int n_in,
                              void* d_out, int out_size, void* d_ws, size_t ws_size,
                              hipStream_t stream)
{
    const float* x      = (const float*)d_in[0];
    const float* ln1_g  = (const float*)d_in[1];
    const float* ln1_b  = (const float*)d_in[2];
    const float* ln2_g  = (const float*)d_in[3];
    const float* ln2_b  = (const float*)d_in[4];
    const float* qkv_w  = (const float*)d_in[5];
    const float* qkv_b  = (const float*)d_in[6];
    const float* out_w  = (const float*)d_in[7];
    const float* out_b  = (const float*)d_in[8];
    const float* fc1_w  = (const float*)d_in[9];
    const float* fc1_b  = (const float*)d_in[10];
    const float* fc2_w  = (const float*)d_in[11];
    const float* fc2_b  = (const float*)d_in[12];
    (void)in_sizes; (void)n_in; (void)out_size; (void)ws_size;

    char* p = (char*)d_ws;
    ushort* qkvb  = (ushort*)p;                 p += (size_t)TSEQ * DFF * 2;          // also gelu-out
    ushort* hb    = (ushort*)p;                 p += (size_t)TSEQ * DMODEL * 2;
    ushort* attnb = (ushort*)p;                 p += (size_t)TSEQ * DMODEL * 2;
    float*  x2    = (float*)p;                  p += (size_t)TSEQ * DMODEL * 4;
    ushort* qkv_wT = (ushort*)p;                p += (size_t)(3 * DMODEL) * DMODEL * 2;
    ushort* out_wT = (ushort*)p;                p += (size_t)DMODEL * DMODEL * 2;
    ushort* fc1_wT = (ushort*)p;                p += (size_t)DFF * DMODEL * 2;
    ushort* fc2_wT = (ushort*)p;                p += (size_t)DMODEL * DFF * 2;
    ushort* Opart  = (ushort*)p;                p += (size_t)8 * TSEQ * DMODEL * 2;
    float*  mlbuf  = (float*)p;                 p += (size_t)8 * NHEADS * TSEQ * 4;
    ushort* vTb    = (ushort*)p;                p += (size_t)DMODEL * TSEQ * 2;
    ushort* gb = qkvb;

    transpose_cast_kernel<<<dim3(DMODEL / 32, 3 * DMODEL / 32), 256, 0, stream>>>(qkv_w, qkv_wT, DMODEL, 3 * DMODEL);
    transpose_cast_kernel<<<dim3(DMODEL / 32, DMODEL / 32), 256, 0, stream>>>(out_w, out_wT, DMODEL, DMODEL);
    transpose_cast_kernel<<<dim3(DMODEL / 32, DFF / 32), 256, 0, stream>>>(fc1_w, fc1_wT, DMODEL, DFF);
    transpose_cast_kernel<<<dim3(DFF / 32, DMODEL / 32), 256, 0, stream>>>(fc2_w, fc2_wT, DFF, DMODEL);

    ln_half_kernel<<<TSEQ, 256, 0, stream>>>(x, ln1_g, ln1_b, hb);
    gemm_kernel<0><<<dim3(TSEQ / 128, 3 * DMODEL / 128), 256, 0, stream>>>(
        hb, qkv_wT, qkv_b, nullptr, qkvb, TSEQ, 3 * DMODEL, DMODEL);
    vtrans_kernel<<<dim3(TSEQ / 64, DMODEL / 64), 256, 0, stream>>>(qkvb, vTb);
    attn_kernel<<<dim3(TSEQ / 256, NHEADS, 8), 512, 0, stream>>>(qkvb, vTb, Opart, mlbuf);
    attn_combine_kernel<<<(TSEQ * DMODEL / 4) / 256, 256, 0, stream>>>(Opart, mlbuf, attnb);
    gemm_n64_kernel<2><<<dim3(TSEQ / 128, DMODEL / 64), 256, 0, stream>>>(
        attnb, out_wT, out_b, x, x2, TSEQ, DMODEL, DMODEL);
    ln_half_kernel<<<TSEQ, 256, 0, stream>>>(x2, ln2_g, ln2_b, hb);
    gemm_kernel<1><<<dim3(TSEQ / 128, DFF / 128), 256, 0, stream>>>(
        hb, fc1_wT, fc1_b, nullptr, gb, TSEQ, DFF, DMODEL);
    gemm_n64_kernel<2><<<dim3(TSEQ / 128, DMODEL / 64), 256, 0, stream>>>(
        gb, fc2_wT, fc2_b, x2, (float*)d_out, TSEQ, DMODEL, DFF);
}

// Round 15
// 218.799 us; speedup vs baseline: 1.0797x; 1.0297x over previous
//
#include <hip/hip_runtime.h>
#include <hip/hip_bf16.h>
#include <math.h>

#define TSEQ 4096
#define DMODEL 768
#define DFF 3072
#define NHEADS 12
#define HDIM 64

typedef __attribute__((ext_vector_type(8))) short short8;
typedef __attribute__((ext_vector_type(4))) float f32x4;
typedef unsigned short ushort;
typedef unsigned int uint;

typedef __attribute__((address_space(1))) ushort as1_ushort;
typedef __attribute__((address_space(3))) ushort as3_ushort;

__device__ __forceinline__ void gl_lds16(const ushort* g, const ushort* l) {
    __builtin_amdgcn_global_load_lds((as1_ushort*)(uintptr_t)g,
                                     (as3_ushort*)(uint)(uintptr_t)l, 16, 0, 0);
}

__device__ __forceinline__ ushort f2bf(float f) {
    union { float f; unsigned i; } c; c.f = f;
    unsigned x = c.i;
    unsigned r = x + 0x7FFFu + ((x >> 16) & 1u);
    return (ushort)(r >> 16);
}
__device__ __forceinline__ float asf(uint u) {
    union { unsigned i; float f; } c; c.i = u; return c.f;
}
// tanh-form GELU
__device__ __forceinline__ float gelu_fast(float v) {
    float y = v * (0.7978845608f + 0.03567740814f * v * v);
    float u = exp2f(y * -2.8853900817779268f);
    float r;
    asm("v_rcp_f32 %0, %1" : "=v"(r) : "v"(1.f + u));
    return v * r;
}

// ---------------- LayerNorm * 0.5 -> bf16 ----------------
__global__ __launch_bounds__(256) void ln_half_kernel(
    const float* __restrict__ x, const float* __restrict__ g,
    const float* __restrict__ b, ushort* __restrict__ out)
{
    int row = blockIdx.x;
    const float* xr = x + (size_t)row * DMODEL;
    float v[3];
    float s = 0.f, s2 = 0.f;
    #pragma unroll
    for (int i = 0; i < 3; i++) {
        v[i] = xr[threadIdx.x + 256 * i];
        s += v[i]; s2 += v[i] * v[i];
    }
    #pragma unroll
    for (int m = 1; m < 64; m <<= 1) { s += __shfl_xor(s, m, 64); s2 += __shfl_xor(s2, m, 64); }
    __shared__ float ss[4], ss2[4];
    int wid = threadIdx.x >> 6;
    if ((threadIdx.x & 63) == 0) { ss[wid] = s; ss2[wid] = s2; }
    __syncthreads();
    s = ss[0] + ss[1] + ss[2] + ss[3];
    s2 = ss2[0] + ss2[1] + ss2[2] + ss2[3];
    float mu = s * (1.f / DMODEL);
    float var = s2 * (1.f / DMODEL) - mu * mu;
    float rs = rsqrtf(var + 1e-5f);
    #pragma unroll
    for (int i = 0; i < 3; i++) {
        int c = threadIdx.x + 256 * i;
        float h = (v[i] - mu) * rs * g[c] + b[c];
        out[(size_t)row * DMODEL + c] = f2bf(h * 0.5f);
    }
}

// ---------------- transpose + cast: in [K,N] f32 -> out [N,K] bf16 ----------------
__global__ __launch_bounds__(256) void transpose_cast_kernel(
    const float* __restrict__ in, ushort* __restrict__ out, int K, int N)
{
    __shared__ float tile[32][33];
    int k0 = blockIdx.x * 32, n0 = blockIdx.y * 32;
    int c = threadIdx.x & 31, r0 = threadIdx.x >> 5;
    #pragma unroll
    for (int i = 0; i < 4; i++) {
        int r = r0 + i * 8;
        tile[r][c] = in[(size_t)(k0 + r) * N + n0 + c];
    }
    __syncthreads();
    #pragma unroll
    for (int i = 0; i < 4; i++) {
        int r = r0 + i * 8;
        out[(size_t)(n0 + r) * K + k0 + c] = f2bf(tile[c][r]);
    }
}

// ---------------- V transpose: qkvb [T,2304] (V cols 1536..2303) -> vT [768][T] bf16 ----------------
__global__ __launch_bounds__(256) void vtrans_kernel(
    const ushort* __restrict__ qkvb, ushort* __restrict__ vT)
{
    __shared__ ushort tile[64][72];
    int t0 = blockIdx.x * 64, d0 = blockIdx.y * 64;
    int tid = threadIdx.x;
    int r = tid >> 2, c = (tid & 3) * 16;
    const ushort* src = qkvb + (size_t)(t0 + r) * 2304 + 1536 + d0 + c;
    *(short8*)&tile[r][c]     = *(const short8*)src;
    *(short8*)&tile[r][c + 8] = *(const short8*)(src + 8);
    __syncthreads();
    int d = tid & 63, gq = tid >> 6;
    short8 w0, w1;
    #pragma unroll
    for (int i = 0; i < 8; i++) w0[i] = (short)tile[gq * 16 + i][d];
    #pragma unroll
    for (int i = 0; i < 8; i++) w1[i] = (short)tile[gq * 16 + 8 + i][d];
    ushort* dst = vT + (size_t)(d0 + d) * TSEQ + t0 + gq * 16;
    *(short8*)dst       = w0;
    *(short8*)(dst + 8) = w1;
}

// ---------------- GEMM BN=128 ----------------
template<int EPI>
__global__ __launch_bounds__(256) void gemm_kernel(
    const ushort* __restrict__ A, const ushort* __restrict__ Bt,
    const float* __restrict__ bias, const float* __restrict__ res,
    void* __restrict__ out, int M, int N, int K)
{
    __shared__ ushort As[2][128 * 32];
    __shared__ ushort Bs[2][128 * 32];
    int bm = blockIdx.x * 128, bn = blockIdx.y * 128;
    int tid = threadIdx.x;
    int wid = tid >> 6, lane = tid & 63;
    int wm = (wid >> 1) * 64, wn = (wid & 1) * 64;
    int lg = lane >> 4, lr = lane & 15;
    int srow = lane >> 2, scol = (lane & 3) * 8;
    f32x4 acc[4][4] = {};

    const ushort* ga0 = A  + (size_t)(bm + wid * 16 + srow) * K + scol;
    const ushort* ga1 = A  + (size_t)(bm + 64 + wid * 16 + srow) * K + scol;
    const ushort* gb0 = Bt + (size_t)(bn + wid * 16 + srow) * K + scol;
    const ushort* gb1 = Bt + (size_t)(bn + 64 + wid * 16 + srow) * K + scol;

    gl_lds16(ga0, &As[0][wid * 512]);
    gl_lds16(ga1, &As[0][2048 + wid * 512]);
    gl_lds16(gb0, &Bs[0][wid * 512]);
    gl_lds16(gb1, &Bs[0][2048 + wid * 512]);

    int nt = K >> 5;
    for (int t = 0; t < nt; t++) {
        int cur = t & 1;
        __syncthreads();
        if (t + 1 < nt) {
            int k0 = (t + 1) << 5;
            int nb = cur ^ 1;
            gl_lds16(ga0 + k0, &As[nb][wid * 512]);
            gl_lds16(ga1 + k0, &As[nb][2048 + wid * 512]);
            gl_lds16(gb0 + k0, &Bs[nb][wid * 512]);
            gl_lds16(gb1 + k0, &Bs[nb][2048 + wid * 512]);
        }
        short8 a[4], b[4];
        #pragma unroll
        for (int mi = 0; mi < 4; mi++) a[mi] = *(const short8*)&As[cur][(wm + mi * 16 + lr) * 32 + lg * 8];
        #pragma unroll
        for (int ni = 0; ni < 4; ni++) b[ni] = *(const short8*)&Bs[cur][(wn + ni * 16 + lr) * 32 + lg * 8];
        #pragma unroll
        for (int mi = 0; mi < 4; mi++)
            #pragma unroll
            for (int ni = 0; ni < 4; ni++)
                acc[mi][ni] = __builtin_amdgcn_mfma_f32_16x16x32_bf16(a[mi], b[ni], acc[mi][ni], 0, 0, 0);
    }

    #pragma unroll
    for (int mi = 0; mi < 4; mi++) {
        #pragma unroll
        for (int ni = 0; ni < 4; ni++) {
            int col = bn + wn + ni * 16 + lr;
            float bv = bias[col];
            #pragma unroll
            for (int r = 0; r < 4; r++) {
                int row = bm + wm + mi * 16 + lg * 4 + r;
                float v = acc[mi][ni][r] + bv;
                size_t idx = (size_t)row * N + col;
                if (EPI == 0) {
                    ((ushort*)out)[idx] = f2bf(v);
                } else if (EPI == 1) {
                    ((ushort*)out)[idx] = f2bf(gelu_fast(v));
                } else {
                    ((float*)out)[idx] = v + res[idx];
                }
            }
        }
    }
}

// ---------------- GEMM BN=64 (skinny-N: out-proj, FC2) ----------------
template<int EPI>
__global__ __launch_bounds__(256) void gemm_n64_kernel(
    const ushort* __restrict__ A, const ushort* __restrict__ Bt,
    const float* __restrict__ bias, const float* __restrict__ res,
    void* __restrict__ out, int M, int N, int K)
{
    __shared__ ushort As[2][128 * 32];
    __shared__ ushort Bs[2][64 * 32];
    int bm = blockIdx.x * 128, bn = blockIdx.y * 64;
    int tid = threadIdx.x;
    int wid = tid >> 6, lane = tid & 63;
    int wm = (wid >> 1) * 64, wn = (wid & 1) * 32;
    int lg = lane >> 4, lr = lane & 15;
    int srow = lane >> 2, scol = (lane & 3) * 8;
    f32x4 acc[4][2] = {};

    const ushort* ga0 = A  + (size_t)(bm + wid * 16 + srow) * K + scol;
    const ushort* ga1 = A  + (size_t)(bm + 64 + wid * 16 + srow) * K + scol;
    const ushort* gb0 = Bt + (size_t)(bn + wid * 16 + srow) * K + scol;

    gl_lds16(ga0, &As[0][wid * 512]);
    gl_lds16(ga1, &As[0][2048 + wid * 512]);
    gl_lds16(gb0, &Bs[0][wid * 512]);

    int nt = K >> 5;
    for (int t = 0; t < nt; t++) {
        int cur = t & 1;
        __syncthreads();
        if (t + 1 < nt) {
            int k0 = (t + 1) << 5;
            int nb = cur ^ 1;
            gl_lds16(ga0 + k0, &As[nb][wid * 512]);
            gl_lds16(ga1 + k0, &As[nb][2048 + wid * 512]);
            gl_lds16(gb0 + k0, &Bs[nb][wid * 512]);
        }
        short8 a[4], b[2];
        #pragma unroll
        for (int mi = 0; mi < 4; mi++) a[mi] = *(const short8*)&As[cur][(wm + mi * 16 + lr) * 32 + lg * 8];
        #pragma unroll
        for (int ni = 0; ni < 2; ni++) b[ni] = *(const short8*)&Bs[cur][(wn + ni * 16 + lr) * 32 + lg * 8];
        #pragma unroll
        for (int mi = 0; mi < 4; mi++)
            #pragma unroll
            for (int ni = 0; ni < 2; ni++)
                acc[mi][ni] = __builtin_amdgcn_mfma_f32_16x16x32_bf16(a[mi], b[ni], acc[mi][ni], 0, 0, 0);
    }

    #pragma unroll
    for (int mi = 0; mi < 4; mi++) {
        #pragma unroll
        for (int ni = 0; ni < 2; ni++) {
            int col = bn + wn + ni * 16 + lr;
            float bv = bias[col];
            #pragma unroll
            for (int r = 0; r < 4; r++) {
                int row = bm + wm + mi * 16 + lg * 4 + r;
                float v = acc[mi][ni][r] + bv;
                size_t idx = (size_t)row * N + col;
                if (EPI == 0) {
                    ((ushort*)out)[idx] = f2bf(v);
                } else if (EPI == 1) {
                    ((ushort*)out)[idx] = f2bf(gelu_fast(v));
                } else {
                    ((float*)out)[idx] = v + res[idx];
                }
            }
        }
    }
}

// ---------------- flash attention (split-K x4, QBLK=256, 52KB LDS, XCD-local KV) ----------------
// 1-D grid, work decode: combo = bid % 48 -> (head, split); qblk = bid / 48.
// For fixed combo the 16 q-blocks have ids == combo (mod 8) -> same XCD -> the
// 256KB KV panel lives in ONE L2 (T1). 8 waves x 32 q-rows, 2-buffer K/V via
// gl_lds (XOR-unit source swizzle), Q staged via dest-XOR LDS, PV in two k-32
// halves on [256][40] P scratch, static-max softmax, ones-MFMA lsum, setprio.
__global__ __launch_bounds__(512) void attn_kernel(
    const ushort* __restrict__ qkv, const ushort* __restrict__ vT,
    ushort* __restrict__ Opart, float* __restrict__ ml)
{
    int combo = blockIdx.x % 48;
    int qblk  = blockIdx.x / 48;
    int h     = combo >> 2;
    int split = combo & 3;
    __shared__ ushort smem[16384 + 256 * 40];    // K/V dbuf (32KB) + P scratch (20KB)
    ushort* Ps = smem + 16384;
    int tid = threadIdx.x, wid = tid >> 6, lane = tid & 63;
    int lg = lane >> 4, lr = lane & 15;
    const float C1 = 0.18033688011112042f;   // 0.125 * log2(e)
    const float KC = 12.0f * C1;
    int x7 = lr & 7;

    { // stage Q: dest-XOR swizzled LDS (bank-spread), linear global source
        int row = tid >> 1;
        int u0 = (tid & 1) * 4;
        int r7 = row & 7;
        const ushort* src = qkv + (size_t)(qblk * 256 + row) * 2304 + h * HDIM;
        #pragma unroll
        for (int i = 0; i < 4; i++) {
            int u = u0 + i;
            *(short8*)&smem[row * 64 + ((u ^ r7) * 8)] = *(const short8*)(src + (size_t)(u * 8));
        }
    }
    int q0row = (wid * 32 + lr) * 64;
    int q1row = q0row + 16 * 64;
    short8 qa0 = *(const short8*)&smem[q0row + (lg ^ x7) * 8];
    short8 qa1 = *(const short8*)&smem[q0row + ((4 + lg) ^ x7) * 8];
    short8 qb0 = *(const short8*)&smem[q1row + (lg ^ x7) * 8];
    short8 qb1 = *(const short8*)&smem[q1row + ((4 + lg) ^ x7) * 8];
    __syncthreads();    // everyone done reading Q before K/V overwrite

    short8 vone;
    #pragma unroll
    for (int i = 0; i < 8; i++) vone[i] = (short)0x3F80;

    // staging geometry (dest linear [64][64], source 16B-unit XOR swizzle by row&7)
    int krow = tid >> 3;
    int kunit = (tid & 7) ^ (krow & 7);
    const ushort* kg = qkv + (size_t)(split * 1024 + krow) * 2304 + DMODEL + h * HDIM + kunit * 8;
    const ushort* vgp = vT + (size_t)(h * HDIM + krow) * TSEQ + split * 1024 + kunit * 8;

    gl_lds16(kg, &smem[tid * 8]);             // K buf0 = smem[0..4095]
    gl_lds16(vgp, &smem[8192 + tid * 8]);     // V buf0 = smem[8192..12287]
    kg += 64 * 2304;
    vgp += 64;

    f32x4 o0[4] = {}, o1[4] = {};
    f32x4 s0sum = {}, s1sum = {};
    const int NT = 16;                        // tiles per split (4096/64/4)
    int prow0 = (wid * 32 + lr) * 40;
    int prow1 = prow0 + 16 * 40;

    for (int kt = 0; kt < NT; kt++) {
        int cur = kt & 1, nb = cur ^ 1;
        __syncthreads();                     // buf[cur] ready (drains vmcnt)
        if (kt + 1 < NT) {
            gl_lds16(kg, &smem[nb * 4096 + tid * 8]);
            gl_lds16(vgp, &smem[8192 + nb * 4096 + tid * 8]);
            kg += 64 * 2304;
            vgp += 64;
        }
        const ushort* kb = &smem[cur * 4096];
        const ushort* vb = &smem[8192 + cur * 4096];

        // S^T = K Q^T for both q-subsets (K-frags read once)
        f32x4 st0[4] = {}, st1[4] = {};
        __builtin_amdgcn_s_setprio(1);
        #pragma unroll
        for (int ki = 0; ki < 4; ki++) {
            const ushort* kr = &kb[(ki * 16 + lr) * 64];
            short8 k0 = *(const short8*)&kr[(lg ^ x7) * 8];
            short8 k1 = *(const short8*)&kr[((4 + lg) ^ x7) * 8];
            st0[ki] = __builtin_amdgcn_mfma_f32_16x16x32_bf16(k0, qa0, st0[ki], 0, 0, 0);
            st0[ki] = __builtin_amdgcn_mfma_f32_16x16x32_bf16(k1, qa1, st0[ki], 0, 0, 0);
            st1[ki] = __builtin_amdgcn_mfma_f32_16x16x32_bf16(k0, qb0, st1[ki], 0, 0, 0);
            st1[ki] = __builtin_amdgcn_mfma_f32_16x16x32_bf16(k1, qb1, st1[ki], 0, 0, 0);
        }
        __builtin_amdgcn_s_setprio(0);

        // static-max exp + pack into dword pairs
        uint2 c0[4], c1[4];
        #pragma unroll
        for (int ki = 0; ki < 4; ki++) {
            #pragma unroll
            for (int r = 0; r < 4; r++) st0[ki][r] = exp2f(st0[ki][r] * C1 - KC);
            asm("v_cvt_pk_bf16_f32 %0, %1, %2" : "=v"(c0[ki].x) : "v"(st0[ki][0]), "v"(st0[ki][1]));
            asm("v_cvt_pk_bf16_f32 %0, %1, %2" : "=v"(c0[ki].y) : "v"(st0[ki][2]), "v"(st0[ki][3]));
        }
        #pragma unroll
        for (int ki = 0; ki < 4; ki++) {
            #pragma unroll
            for (int r = 0; r < 4; r++) st1[ki][r] = exp2f(st1[ki][r] * C1 - KC);
            asm("v_cvt_pk_bf16_f32 %0, %1, %2" : "=v"(c1[ki].x) : "v"(st1[ki][0]), "v"(st1[ki][1]));
            asm("v_cvt_pk_bf16_f32 %0, %1, %2" : "=v"(c1[ki].y) : "v"(st1[ki][2]), "v"(st1[ki][3]));
        }

        // ---- half 0: k in [0,32) ----
        *(uint2*)&Ps[prow0 + lg * 4]      = c0[0];
        *(uint2*)&Ps[prow0 + 16 + lg * 4] = c0[1];
        *(uint2*)&Ps[prow1 + lg * 4]      = c1[0];
        *(uint2*)&Ps[prow1 + 16 + lg * 4] = c1[1];
        {
            short8 pa00 = *(const short8*)&Ps[prow0 + lg * 8];
            short8 pa10 = *(const short8*)&Ps[prow1 + lg * 8];
            __builtin_amdgcn_s_setprio(1);
            s0sum = __builtin_amdgcn_mfma_f32_16x16x32_bf16(pa00, vone, s0sum, 0, 0, 0);
            s1sum = __builtin_amdgcn_mfma_f32_16x16x32_bf16(pa10, vone, s1sum, 0, 0, 0);
            #pragma unroll
            for (int ni = 0; ni < 4; ni++) {
                short8 b0 = *(const short8*)&vb[(ni * 16 + lr) * 64 + (lg ^ x7) * 8];
                o0[ni] = __builtin_amdgcn_mfma_f32_16x16x32_bf16(pa00, b0, o0[ni], 0, 0, 0);
                o1[ni] = __builtin_amdgcn_mfma_f32_16x16x32_bf16(pa10, b0, o1[ni], 0, 0, 0);
            }
            __builtin_amdgcn_s_setprio(0);
        }
        // ---- half 1: k in [32,64) (reuses same P scratch cols) ----
        *(uint2*)&Ps[prow0 + lg * 4]      = c0[2];
        *(uint2*)&Ps[prow0 + 16 + lg * 4] = c0[3];
        *(uint2*)&Ps[prow1 + lg * 4]      = c1[2];
        *(uint2*)&Ps[prow1 + 16 + lg * 4] = c1[3];
        {
            short8 pa01 = *(const short8*)&Ps[prow0 + lg * 8];
            short8 pa11 = *(const short8*)&Ps[prow1 + lg * 8];
            __builtin_amdgcn_s_setprio(1);
            s0sum = __builtin_amdgcn_mfma_f32_16x16x32_bf16(pa01, vone, s0sum, 0, 0, 0);
            s1sum = __builtin_amdgcn_mfma_f32_16x16x32_bf16(pa11, vone, s1sum, 0, 0, 0);
            #pragma unroll
            for (int ni = 0; ni < 4; ni++) {
                short8 b1 = *(const short8*)&vb[(ni * 16 + lr) * 64 + ((4 + lg) ^ x7) * 8];
                o0[ni] = __builtin_amdgcn_mfma_f32_16x16x32_bf16(pa01, b1, o0[ni], 0, 0, 0);
                o1[ni] = __builtin_amdgcn_mfma_f32_16x16x32_bf16(pa11, b1, o1[ni], 0, 0, 0);
            }
            __builtin_amdgcn_s_setprio(0);
        }
    }

    // epilogue
    if (lr == 0) {
        #pragma unroll
        for (int r = 0; r < 4; r++) {
            int q0 = qblk * 256 + wid * 32 + lg * 4 + r;
            ml[((size_t)split * NHEADS + h) * TSEQ + q0]      = s0sum[r];
            ml[((size_t)split * NHEADS + h) * TSEQ + q0 + 16] = s1sum[r];
        }
    }
    #pragma unroll
    for (int ni = 0; ni < 4; ni++)
        #pragma unroll
        for (int r = 0; r < 4; r++) {
            int q0 = qblk * 256 + wid * 32 + lg * 4 + r;
            int dcol = ni * 16 + lr;
            Opart[((size_t)split * TSEQ + q0) * DMODEL + h * HDIM + dcol]      = f2bf(o0[ni][r]);
            Opart[((size_t)split * TSEQ + q0 + 16) * DMODEL + h * HDIM + dcol] = f2bf(o1[ni][r]);
        }
}

// ---------------- combine 4 split partials -> attn bf16 ----------------
__global__ __launch_bounds__(256) void attn_combine_kernel(
    const ushort* __restrict__ Opart, const float* __restrict__ ml,
    ushort* __restrict__ attnb)
{
    int gid = blockIdx.x * 256 + threadIdx.x;
    int q = gid / 192;
    int c = (gid - q * 192) * 4;
    int hh = c >> 6;
    float denom = 0.f;
    float a0 = 0.f, a1 = 0.f, a2 = 0.f, a3 = 0.f;
    #pragma unroll
    for (int s = 0; s < 4; s++) {
        denom += ml[((size_t)s * NHEADS + hh) * TSEQ + q];
        uint2 ov = *(const uint2*)&Opart[((size_t)s * TSEQ + q) * DMODEL + c];
        a0 += asf(ov.x << 16);
        a1 += asf(ov.x & 0xFFFF0000u);
        a2 += asf(ov.y << 16);
        a3 += asf(ov.y & 0xFFFF0000u);
    }
    float rd = 1.f / denom;
    uint2 stv;
    stv.x = (uint)f2bf(a0 * rd) | ((uint)f2bf(a1 * rd) << 16);
    stv.y = (uint)f2bf(a2 * rd) | ((uint)f2bf(a3 * rd) << 16);
    *(uint2*)&attnb[(size_t)q * DMODEL + c] = stv;
}

// ---------------- host launch ----------------
extern "C" void kernel_launch(void* const* d_in, const int* in_sizes, int n_in,
                              void* d_out, int out_size, void* d_ws, size_t ws_size,
                              hipStream_t stream)
{
    const float* x      = (const float*)d_in[0];
    const float* ln1_g  = (const float*)d_in[1];
    const float* ln1_b  = (const float*)d_in[2];
    const float* ln2_g  = (const float*)d_in[3];
    const float* ln2_b  = (const float*)d_in[4];
    const float* qkv_w  = (const float*)d_in[5];
    const float* qkv_b  = (const float*)d_in[6];
    const float* out_w  = (const float*)d_in[7];
    const float* out_b  = (const float*)d_in[8];
    const float* fc1_w  = (const float*)d_in[9];
    const float* fc1_b  = (const float*)d_in[10];
    const float* fc2_w  = (const float*)d_in[11];
    const float* fc2_b  = (const float*)d_in[12];
    (void)in_sizes; (void)n_in; (void)out_size; (void)ws_size;

    char* p = (char*)d_ws;
    ushort* qkvb  = (ushort*)p;                 p += (size_t)TSEQ * DFF * 2;          // also gelu-out
    ushort* hb    = (ushort*)p;                 p += (size_t)TSEQ * DMODEL * 2;
    ushort* attnb = (ushort*)p;                 p += (size_t)TSEQ * DMODEL * 2;
    float*  x2    = (float*)p;                  p += (size_t)TSEQ * DMODEL * 4;
    ushort* qkv_wT = (ushort*)p;                p += (size_t)(3 * DMODEL) * DMODEL * 2;
    ushort* out_wT = (ushort*)p;                p += (size_t)DMODEL * DMODEL * 2;
    ushort* fc1_wT = (ushort*)p;                p += (size_t)DFF * DMODEL * 2;
    ushort* fc2_wT = (ushort*)p;                p += (size_t)DMODEL * DFF * 2;
    ushort* Opart  = (ushort*)p;                p += (size_t)4 * TSEQ * DMODEL * 2;
    float*  mlbuf  = (float*)p;                 p += (size_t)4 * NHEADS * TSEQ * 4;
    ushort* vTb    = (ushort*)p;                p += (size_t)DMODEL * TSEQ * 2;
    ushort* gb = qkvb;

    transpose_cast_kernel<<<dim3(DMODEL / 32, 3 * DMODEL / 32), 256, 0, stream>>>(qkv_w, qkv_wT, DMODEL, 3 * DMODEL);
    transpose_cast_kernel<<<dim3(DMODEL / 32, DMODEL / 32), 256, 0, stream>>>(out_w, out_wT, DMODEL, DMODEL);
    transpose_cast_kernel<<<dim3(DMODEL / 32, DFF / 32), 256, 0, stream>>>(fc1_w, fc1_wT, DMODEL, DFF);
    transpose_cast_kernel<<<dim3(DFF / 32, DMODEL / 32), 256, 0, stream>>>(fc2_w, fc2_wT, DFF, DMODEL);

    ln_half_kernel<<<TSEQ, 256, 0, stream>>>(x, ln1_g, ln1_b, hb);
    gemm_kernel<0><<<dim3(TSEQ / 128, 3 * DMODEL / 128), 256, 0, stream>>>(
        hb, qkv_wT, qkv_b, nullptr, qkvb, TSEQ, 3 * DMODEL, DMODEL);
    vtrans_kernel<<<dim3(TSEQ / 64, DMODEL / 64), 256, 0, stream>>>(qkvb, vTb);
    attn_kernel<<<dim3((TSEQ / 256) * NHEADS * 4), 512, 0, stream>>>(qkvb, vTb, Opart, mlbuf);
    attn_combine_kernel<<<(TSEQ * DMODEL / 4) / 256, 256, 0, stream>>>(Opart, mlbuf, attnb);
    gemm_n64_kernel<2><<<dim3(TSEQ / 128, DMODEL / 64), 256, 0, stream>>>(
        attnb, out_wT, out_b, x, x2, TSEQ, DMODEL, DMODEL);
    ln_half_kernel<<<TSEQ, 256, 0, stream>>>(x2, ln2_g, ln2_b, hb);
    gemm_kernel<1><<<dim3(TSEQ / 128, DFF / 128), 256, 0, stream>>>(
        hb, fc1_wT, fc1_b, nullptr, gb, TSEQ, DFF, DMODEL);
    gemm_n64_kernel<2><<<dim3(TSEQ / 128, DMODEL / 64), 256, 0, stream>>>(
        gb, fc2_wT, fc2_b, x2, (float*)d_out, TSEQ, DMODEL, DFF);
}

// Round 16
// 212.159 us; speedup vs baseline: 1.1134x; 1.0313x over previous
//
#include <hip/hip_runtime.h>
#include <hip/hip_bf16.h>
#include <math.h>

#define TSEQ 4096
#define DMODEL 768
#define DFF 3072
#define NHEADS 12
#define HDIM 64

typedef __attribute__((ext_vector_type(8))) short short8;
typedef __attribute__((ext_vector_type(4))) float f32x4;
typedef unsigned short ushort;
typedef unsigned int uint;

typedef __attribute__((address_space(1))) ushort as1_ushort;
typedef __attribute__((address_space(3))) ushort as3_ushort;

__device__ __forceinline__ void gl_lds16(const ushort* g, const ushort* l) {
    __builtin_amdgcn_global_load_lds((as1_ushort*)(uintptr_t)g,
                                     (as3_ushort*)(uint)(uintptr_t)l, 16, 0, 0);
}

__device__ __forceinline__ ushort f2bf(float f) {
    union { float f; unsigned i; } c; c.f = f;
    unsigned x = c.i;
    unsigned r = x + 0x7FFFu + ((x >> 16) & 1u);
    return (ushort)(r >> 16);
}
__device__ __forceinline__ float asf(uint u) {
    union { unsigned i; float f; } c; c.i = u; return c.f;
}
// tanh-form GELU
__device__ __forceinline__ float gelu_fast(float v) {
    float y = v * (0.7978845608f + 0.03567740814f * v * v);
    float u = exp2f(y * -2.8853900817779268f);
    float r;
    asm("v_rcp_f32 %0, %1" : "=v"(r) : "v"(1.f + u));
    return v * r;
}

// ---------------- LayerNorm * 0.5 -> bf16 ----------------
__global__ __launch_bounds__(256) void ln_half_kernel(
    const float* __restrict__ x, const float* __restrict__ g,
    const float* __restrict__ b, ushort* __restrict__ out)
{
    int row = blockIdx.x;
    const float* xr = x + (size_t)row * DMODEL;
    float v[3];
    float s = 0.f, s2 = 0.f;
    #pragma unroll
    for (int i = 0; i < 3; i++) {
        v[i] = xr[threadIdx.x + 256 * i];
        s += v[i]; s2 += v[i] * v[i];
    }
    #pragma unroll
    for (int m = 1; m < 64; m <<= 1) { s += __shfl_xor(s, m, 64); s2 += __shfl_xor(s2, m, 64); }
    __shared__ float ss[4], ss2[4];
    int wid = threadIdx.x >> 6;
    if ((threadIdx.x & 63) == 0) { ss[wid] = s; ss2[wid] = s2; }
    __syncthreads();
    s = ss[0] + ss[1] + ss[2] + ss[3];
    s2 = ss2[0] + ss2[1] + ss2[2] + ss2[3];
    float mu = s * (1.f / DMODEL);
    float var = s2 * (1.f / DMODEL) - mu * mu;
    float rs = rsqrtf(var + 1e-5f);
    #pragma unroll
    for (int i = 0; i < 3; i++) {
        int c = threadIdx.x + 256 * i;
        float h = (v[i] - mu) * rs * g[c] + b[c];
        out[(size_t)row * DMODEL + c] = f2bf(h * 0.5f);
    }
}

// ---------------- transpose + cast: in [K,N] f32 -> out [N,K] bf16 ----------------
__global__ __launch_bounds__(256) void transpose_cast_kernel(
    const float* __restrict__ in, ushort* __restrict__ out, int K, int N)
{
    __shared__ float tile[32][33];
    int k0 = blockIdx.x * 32, n0 = blockIdx.y * 32;
    int c = threadIdx.x & 31, r0 = threadIdx.x >> 5;
    #pragma unroll
    for (int i = 0; i < 4; i++) {
        int r = r0 + i * 8;
        tile[r][c] = in[(size_t)(k0 + r) * N + n0 + c];
    }
    __syncthreads();
    #pragma unroll
    for (int i = 0; i < 4; i++) {
        int r = r0 + i * 8;
        out[(size_t)(n0 + r) * K + k0 + c] = f2bf(tile[c][r]);
    }
}

// ---------------- GEMM BN=128 (EPI 0: bias->bf16; 1: bias+GELU->bf16; 2: bias+res->f32;
//                  3: QKV fused — V-range columns (bn>=1536) written TRANSPOSED to vTout) --------
template<int EPI>
__global__ __launch_bounds__(256) void gemm_kernel(
    const ushort* __restrict__ A, const ushort* __restrict__ Bt,
    const float* __restrict__ bias, const float* __restrict__ res,
    void* __restrict__ out, ushort* __restrict__ vTout, int M, int N, int K)
{
    __shared__ ushort As[2][128 * 32];
    __shared__ ushort Bs[2][128 * 32];
    int bm = blockIdx.x * 128, bn = blockIdx.y * 128;
    int tid = threadIdx.x;
    int wid = tid >> 6, lane = tid & 63;
    int wm = (wid >> 1) * 64, wn = (wid & 1) * 64;
    int lg = lane >> 4, lr = lane & 15;
    int srow = lane >> 2, scol = (lane & 3) * 8;
    f32x4 acc[4][4] = {};

    const ushort* ga0 = A  + (size_t)(bm + wid * 16 + srow) * K + scol;
    const ushort* ga1 = A  + (size_t)(bm + 64 + wid * 16 + srow) * K + scol;
    const ushort* gb0 = Bt + (size_t)(bn + wid * 16 + srow) * K + scol;
    const ushort* gb1 = Bt + (size_t)(bn + 64 + wid * 16 + srow) * K + scol;

    gl_lds16(ga0, &As[0][wid * 512]);
    gl_lds16(ga1, &As[0][2048 + wid * 512]);
    gl_lds16(gb0, &Bs[0][wid * 512]);
    gl_lds16(gb1, &Bs[0][2048 + wid * 512]);

    int nt = K >> 5;
    for (int t = 0; t < nt; t++) {
        int cur = t & 1;
        __syncthreads();
        if (t + 1 < nt) {
            int k0 = (t + 1) << 5;
            int nb = cur ^ 1;
            gl_lds16(ga0 + k0, &As[nb][wid * 512]);
            gl_lds16(ga1 + k0, &As[nb][2048 + wid * 512]);
            gl_lds16(gb0 + k0, &Bs[nb][wid * 512]);
            gl_lds16(gb1 + k0, &Bs[nb][2048 + wid * 512]);
        }
        short8 a[4], b[4];
        #pragma unroll
        for (int mi = 0; mi < 4; mi++) a[mi] = *(const short8*)&As[cur][(wm + mi * 16 + lr) * 32 + lg * 8];
        #pragma unroll
        for (int ni = 0; ni < 4; ni++) b[ni] = *(const short8*)&Bs[cur][(wn + ni * 16 + lr) * 32 + lg * 8];
        #pragma unroll
        for (int mi = 0; mi < 4; mi++)
            #pragma unroll
            for (int ni = 0; ni < 4; ni++)
                acc[mi][ni] = __builtin_amdgcn_mfma_f32_16x16x32_bf16(a[mi], b[ni], acc[mi][ni], 0, 0, 0);
    }

    #pragma unroll
    for (int mi = 0; mi < 4; mi++) {
        #pragma unroll
        for (int ni = 0; ni < 4; ni++) {
            int col = bn + wn + ni * 16 + lr;
            float bv = bias[col];
            if (EPI == 3 && bn >= 1536) {
                // V columns -> vT[col-1536][row], 4 consecutive rows packed (8B store)
                int row0 = bm + wm + mi * 16 + lg * 4;
                uint2 pk;
                pk.x = (uint)f2bf(acc[mi][ni][0] + bv) | ((uint)f2bf(acc[mi][ni][1] + bv) << 16);
                pk.y = (uint)f2bf(acc[mi][ni][2] + bv) | ((uint)f2bf(acc[mi][ni][3] + bv) << 16);
                *(uint2*)&vTout[(size_t)(col - 1536) * TSEQ + row0] = pk;
            } else {
                #pragma unroll
                for (int r = 0; r < 4; r++) {
                    int row = bm + wm + mi * 16 + lg * 4 + r;
                    float v = acc[mi][ni][r] + bv;
                    size_t idx = (size_t)row * N + col;
                    if (EPI == 1) {
                        ((ushort*)out)[idx] = f2bf(gelu_fast(v));
                    } else if (EPI == 2) {
                        ((float*)out)[idx] = v + res[idx];
                    } else {
                        ((ushort*)out)[idx] = f2bf(v);
                    }
                }
            }
        }
    }
}

// ---------------- GEMM 64x64 (load-balance for skinny-N: out-proj, FC2) ----------------
// 256 thr / 4 waves (2x2 of 32x32). 1 gl_lds per thread per matrix, XOR-unit
// swizzled source; reads use matching XOR.
template<int EPI>
__global__ __launch_bounds__(256) void gemm_64_kernel(
    const ushort* __restrict__ A, const ushort* __restrict__ Bt,
    const float* __restrict__ bias, const float* __restrict__ res,
    void* __restrict__ out, int M, int N, int K)
{
    __shared__ ushort As[2][64 * 32];
    __shared__ ushort Bs[2][64 * 32];
    int bm = blockIdx.x * 64, bn = blockIdx.y * 64;
    int tid = threadIdx.x;
    int wid = tid >> 6, lane = tid & 63;
    int wm = (wid >> 1) * 32, wn = (wid & 1) * 32;
    int lg = lane >> 4, lr = lane & 15;
    int srow = tid >> 2;
    int sunit = (tid & 3) ^ (srow & 3);
    f32x4 acc[2][2] = {};

    const ushort* ga = A  + (size_t)(bm + srow) * K + sunit * 8;
    const ushort* gb = Bt + (size_t)(bn + srow) * K + sunit * 8;

    gl_lds16(ga, &As[0][tid * 8]);
    gl_lds16(gb, &Bs[0][tid * 8]);

    int nt = K >> 5;
    for (int t = 0; t < nt; t++) {
        int cur = t & 1;
        __syncthreads();
        if (t + 1 < nt) {
            int k0 = (t + 1) << 5;
            int nb = cur ^ 1;
            gl_lds16(ga + k0, &As[nb][tid * 8]);
            gl_lds16(gb + k0, &Bs[nb][tid * 8]);
        }
        short8 a[2], b[2];
        #pragma unroll
        for (int mi = 0; mi < 2; mi++) {
            int row = wm + mi * 16 + lr;
            a[mi] = *(const short8*)&As[cur][row * 32 + ((lg ^ (row & 3)) * 8)];
        }
        #pragma unroll
        for (int ni = 0; ni < 2; ni++) {
            int row = wn + ni * 16 + lr;
            b[ni] = *(const short8*)&Bs[cur][row * 32 + ((lg ^ (row & 3)) * 8)];
        }
        #pragma unroll
        for (int mi = 0; mi < 2; mi++)
            #pragma unroll
            for (int ni = 0; ni < 2; ni++)
                acc[mi][ni] = __builtin_amdgcn_mfma_f32_16x16x32_bf16(a[mi], b[ni], acc[mi][ni], 0, 0, 0);
    }

    #pragma unroll
    for (int mi = 0; mi < 2; mi++) {
        #pragma unroll
        for (int ni = 0; ni < 2; ni++) {
            int col = bn + wn + ni * 16 + lr;
            float bv = bias[col];
            #pragma unroll
            for (int r = 0; r < 4; r++) {
                int row = bm + wm + mi * 16 + lg * 4 + r;
                float v = acc[mi][ni][r] + bv;
                size_t idx = (size_t)row * N + col;
                if (EPI == 0) {
                    ((ushort*)out)[idx] = f2bf(v);
                } else if (EPI == 1) {
                    ((ushort*)out)[idx] = f2bf(gelu_fast(v));
                } else {
                    ((float*)out)[idx] = v + res[idx];
                }
            }
        }
    }
}

// ---------------- flash attention (split-K x4, QBLK=256, 52KB LDS, XCD-local KV) ----------------
__global__ __launch_bounds__(512) void attn_kernel(
    const ushort* __restrict__ qkv, const ushort* __restrict__ vT,
    ushort* __restrict__ Opart, float* __restrict__ ml)
{
    int combo = blockIdx.x % 48;
    int qblk  = blockIdx.x / 48;
    int h     = combo >> 2;
    int split = combo & 3;
    __shared__ ushort smem[16384 + 256 * 40];    // K/V dbuf (32KB) + P scratch (20KB)
    ushort* Ps = smem + 16384;
    int tid = threadIdx.x, wid = tid >> 6, lane = tid & 63;
    int lg = lane >> 4, lr = lane & 15;
    const float C1 = 0.18033688011112042f;   // 0.125 * log2(e)
    const float KC = 12.0f * C1;
    int x7 = lr & 7;

    { // stage Q: dest-XOR swizzled LDS, linear global source
        int row = tid >> 1;
        int u0 = (tid & 1) * 4;
        int r7 = row & 7;
        const ushort* src = qkv + (size_t)(qblk * 256 + row) * 2304 + h * HDIM;
        #pragma unroll
        for (int i = 0; i < 4; i++) {
            int u = u0 + i;
            *(short8*)&smem[row * 64 + ((u ^ r7) * 8)] = *(const short8*)(src + (size_t)(u * 8));
        }
    }
    int q0row = (wid * 32 + lr) * 64;
    int q1row = q0row + 16 * 64;
    short8 qa0 = *(const short8*)&smem[q0row + (lg ^ x7) * 8];
    short8 qa1 = *(const short8*)&smem[q0row + ((4 + lg) ^ x7) * 8];
    short8 qb0 = *(const short8*)&smem[q1row + (lg ^ x7) * 8];
    short8 qb1 = *(const short8*)&smem[q1row + ((4 + lg) ^ x7) * 8];
    __syncthreads();

    short8 vone;
    #pragma unroll
    for (int i = 0; i < 8; i++) vone[i] = (short)0x3F80;

    int krow = tid >> 3;
    int kunit = (tid & 7) ^ (krow & 7);
    const ushort* kg = qkv + (size_t)(split * 1024 + krow) * 2304 + DMODEL + h * HDIM + kunit * 8;
    const ushort* vgp = vT + (size_t)(h * HDIM + krow) * TSEQ + split * 1024 + kunit * 8;

    gl_lds16(kg, &smem[tid * 8]);
    gl_lds16(vgp, &smem[8192 + tid * 8]);
    kg += 64 * 2304;
    vgp += 64;

    f32x4 o0[4] = {}, o1[4] = {};
    f32x4 s0sum = {}, s1sum = {};
    const int NT = 16;
    int prow0 = (wid * 32 + lr) * 40;
    int prow1 = prow0 + 16 * 40;

    for (int kt = 0; kt < NT; kt++) {
        int cur = kt & 1, nb = cur ^ 1;
        __syncthreads();
        if (kt + 1 < NT) {
            gl_lds16(kg, &smem[nb * 4096 + tid * 8]);
            gl_lds16(vgp, &smem[8192 + nb * 4096 + tid * 8]);
            kg += 64 * 2304;
            vgp += 64;
        }
        const ushort* kb = &smem[cur * 4096];
        const ushort* vb = &smem[8192 + cur * 4096];

        f32x4 st0[4] = {}, st1[4] = {};
        __builtin_amdgcn_s_setprio(1);
        #pragma unroll
        for (int ki = 0; ki < 4; ki++) {
            const ushort* kr = &kb[(ki * 16 + lr) * 64];
            short8 k0 = *(const short8*)&kr[(lg ^ x7) * 8];
            short8 k1 = *(const short8*)&kr[((4 + lg) ^ x7) * 8];
            st0[ki] = __builtin_amdgcn_mfma_f32_16x16x32_bf16(k0, qa0, st0[ki], 0, 0, 0);
            st0[ki] = __builtin_amdgcn_mfma_f32_16x16x32_bf16(k1, qa1, st0[ki], 0, 0, 0);
            st1[ki] = __builtin_amdgcn_mfma_f32_16x16x32_bf16(k0, qb0, st1[ki], 0, 0, 0);
            st1[ki] = __builtin_amdgcn_mfma_f32_16x16x32_bf16(k1, qb1, st1[ki], 0, 0, 0);
        }
        __builtin_amdgcn_s_setprio(0);

        uint2 c0[4], c1[4];
        #pragma unroll
        for (int ki = 0; ki < 4; ki++) {
            #pragma unroll
            for (int r = 0; r < 4; r++) st0[ki][r] = exp2f(st0[ki][r] * C1 - KC);
            asm("v_cvt_pk_bf16_f32 %0, %1, %2" : "=v"(c0[ki].x) : "v"(st0[ki][0]), "v"(st0[ki][1]));
            asm("v_cvt_pk_bf16_f32 %0, %1, %2" : "=v"(c0[ki].y) : "v"(st0[ki][2]), "v"(st0[ki][3]));
        }
        #pragma unroll
        for (int ki = 0; ki < 4; ki++) {
            #pragma unroll
            for (int r = 0; r < 4; r++) st1[ki][r] = exp2f(st1[ki][r] * C1 - KC);
            asm("v_cvt_pk_bf16_f32 %0, %1, %2" : "=v"(c1[ki].x) : "v"(st1[ki][0]), "v"(st1[ki][1]));
            asm("v_cvt_pk_bf16_f32 %0, %1, %2" : "=v"(c1[ki].y) : "v"(st1[ki][2]), "v"(st1[ki][3]));
        }

        *(uint2*)&Ps[prow0 + lg * 4]      = c0[0];
        *(uint2*)&Ps[prow0 + 16 + lg * 4] = c0[1];
        *(uint2*)&Ps[prow1 + lg * 4]      = c1[0];
        *(uint2*)&Ps[prow1 + 16 + lg * 4] = c1[1];
        {
            short8 pa00 = *(const short8*)&Ps[prow0 + lg * 8];
            short8 pa10 = *(const short8*)&Ps[prow1 + lg * 8];
            __builtin_amdgcn_s_setprio(1);
            s0sum = __builtin_amdgcn_mfma_f32_16x16x32_bf16(pa00, vone, s0sum, 0, 0, 0);
            s1sum = __builtin_amdgcn_mfma_f32_16x16x32_bf16(pa10, vone, s1sum, 0, 0, 0);
            #pragma unroll
            for (int ni = 0; ni < 4; ni++) {
                short8 b0 = *(const short8*)&vb[(ni * 16 + lr) * 64 + (lg ^ x7) * 8];
                o0[ni] = __builtin_amdgcn_mfma_f32_16x16x32_bf16(pa00, b0, o0[ni], 0, 0, 0);
                o1[ni] = __builtin_amdgcn_mfma_f32_16x16x32_bf16(pa10, b0, o1[ni], 0, 0, 0);
            }
            __builtin_amdgcn_s_setprio(0);
        }
        *(uint2*)&Ps[prow0 + lg * 4]      = c0[2];
        *(uint2*)&Ps[prow0 + 16 + lg * 4] = c0[3];
        *(uint2*)&Ps[prow1 + lg * 4]      = c1[2];
        *(uint2*)&Ps[prow1 + 16 + lg * 4] = c1[3];
        {
            short8 pa01 = *(const short8*)&Ps[prow0 + lg * 8];
            short8 pa11 = *(const short8*)&Ps[prow1 + lg * 8];
            __builtin_amdgcn_s_setprio(1);
            s0sum = __builtin_amdgcn_mfma_f32_16x16x32_bf16(pa01, vone, s0sum, 0, 0, 0);
            s1sum = __builtin_amdgcn_mfma_f32_16x16x32_bf16(pa11, vone, s1sum, 0, 0, 0);
            #pragma unroll
            for (int ni = 0; ni < 4; ni++) {
                short8 b1 = *(const short8*)&vb[(ni * 16 + lr) * 64 + ((4 + lg) ^ x7) * 8];
                o0[ni] = __builtin_amdgcn_mfma_f32_16x16x32_bf16(pa01, b1, o0[ni], 0, 0, 0);
                o1[ni] = __builtin_amdgcn_mfma_f32_16x16x32_bf16(pa11, b1, o1[ni], 0, 0, 0);
            }
            __builtin_amdgcn_s_setprio(0);
        }
    }

    if (lr == 0) {
        #pragma unroll
        for (int r = 0; r < 4; r++) {
            int q0 = qblk * 256 + wid * 32 + lg * 4 + r;
            ml[((size_t)split * NHEADS + h) * TSEQ + q0]      = s0sum[r];
            ml[((size_t)split * NHEADS + h) * TSEQ + q0 + 16] = s1sum[r];
        }
    }
    #pragma unroll
    for (int ni = 0; ni < 4; ni++)
        #pragma unroll
        for (int r = 0; r < 4; r++) {
            int q0 = qblk * 256 + wid * 32 + lg * 4 + r;
            int dcol = ni * 16 + lr;
            Opart[((size_t)split * TSEQ + q0) * DMODEL + h * HDIM + dcol]      = f2bf(o0[ni][r]);
            Opart[((size_t)split * TSEQ + q0 + 16) * DMODEL + h * HDIM + dcol] = f2bf(o1[ni][r]);
        }
}

// ---------------- combine 4 split partials -> attn bf16 ----------------
__global__ __launch_bounds__(256) void attn_combine_kernel(
    const ushort* __restrict__ Opart, const float* __restrict__ ml,
    ushort* __restrict__ attnb)
{
    int gid = blockIdx.x * 256 + threadIdx.x;
    int q = gid / 192;
    int c = (gid - q * 192) * 4;
    int hh = c >> 6;
    float denom = 0.f;
    float a0 = 0.f, a1 = 0.f, a2 = 0.f, a3 = 0.f;
    #pragma unroll
    for (int s = 0; s < 4; s++) {
        denom += ml[((size_t)s * NHEADS + hh) * TSEQ + q];
        uint2 ov = *(const uint2*)&Opart[((size_t)s * TSEQ + q) * DMODEL + c];
        a0 += asf(ov.x << 16);
        a1 += asf(ov.x & 0xFFFF0000u);
        a2 += asf(ov.y << 16);
        a3 += asf(ov.y & 0xFFFF0000u);
    }
    float rd = 1.f / denom;
    uint2 stv;
    stv.x = (uint)f2bf(a0 * rd) | ((uint)f2bf(a1 * rd) << 16);
    stv.y = (uint)f2bf(a2 * rd) | ((uint)f2bf(a3 * rd) << 16);
    *(uint2*)&attnb[(size_t)q * DMODEL + c] = stv;
}

// ---------------- host launch ----------------
extern "C" void kernel_launch(void* const* d_in, const int* in_sizes, int n_in,
                              void* d_out, int out_size, void* d_ws, size_t ws_size,
                              hipStream_t stream)
{
    const float* x      = (const float*)d_in[0];
    const float* ln1_g  = (const float*)d_in[1];
    const float* ln1_b  = (const float*)d_in[2];
    const float* ln2_g  = (const float*)d_in[3];
    const float* ln2_b  = (const float*)d_in[4];
    const float* qkv_w  = (const float*)d_in[5];
    const float* qkv_b  = (const float*)d_in[6];
    const float* out_w  = (const float*)d_in[7];
    const float* out_b  = (const float*)d_in[8];
    const float* fc1_w  = (const float*)d_in[9];
    const float* fc1_b  = (const float*)d_in[10];
    const float* fc2_w  = (const float*)d_in[11];
    const float* fc2_b  = (const float*)d_in[12];
    (void)in_sizes; (void)n_in; (void)out_size; (void)ws_size;

    char* p = (char*)d_ws;
    ushort* qkvb  = (ushort*)p;                 p += (size_t)TSEQ * DFF * 2;          // also gelu-out
    ushort* hb    = (ushort*)p;                 p += (size_t)TSEQ * DMODEL * 2;
    ushort* attnb = (ushort*)p;                 p += (size_t)TSEQ * DMODEL * 2;
    float*  x2    = (float*)p;                  p += (size_t)TSEQ * DMODEL * 4;
    ushort* qkv_wT = (ushort*)p;                p += (size_t)(3 * DMODEL) * DMODEL * 2;
    ushort* out_wT = (ushort*)p;                p += (size_t)DMODEL * DMODEL * 2;
    ushort* fc1_wT = (ushort*)p;                p += (size_t)DFF * DMODEL * 2;
    ushort* fc2_wT = (ushort*)p;                p += (size_t)DMODEL * DFF * 2;
    ushort* Opart  = (ushort*)p;                p += (size_t)4 * TSEQ * DMODEL * 2;
    float*  mlbuf  = (float*)p;                 p += (size_t)4 * NHEADS * TSEQ * 4;
    ushort* vTb    = (ushort*)p;                p += (size_t)DMODEL * TSEQ * 2;
    ushort* gb = qkvb;

    transpose_cast_kernel<<<dim3(DMODEL / 32, 3 * DMODEL / 32), 256, 0, stream>>>(qkv_w, qkv_wT, DMODEL, 3 * DMODEL);
    transpose_cast_kernel<<<dim3(DMODEL / 32, DMODEL / 32), 256, 0, stream>>>(out_w, out_wT, DMODEL, DMODEL);
    transpose_cast_kernel<<<dim3(DMODEL / 32, DFF / 32), 256, 0, stream>>>(fc1_w, fc1_wT, DMODEL, DFF);
    transpose_cast_kernel<<<dim3(DFF / 32, DMODEL / 32), 256, 0, stream>>>(fc2_w, fc2_wT, DFF, DMODEL);

    ln_half_kernel<<<TSEQ, 256, 0, stream>>>(x, ln1_g, ln1_b, hb);
    // QKV GEMM with fused V-transpose epilogue (V cols -> vTb)
    gemm_kernel<3><<<dim3(TSEQ / 128, 3 * DMODEL / 128), 256, 0, stream>>>(
        hb, qkv_wT, qkv_b, nullptr, qkvb, vTb, TSEQ, 3 * DMODEL, DMODEL);
    attn_kernel<<<dim3((TSEQ / 256) * NHEADS * 4), 512, 0, stream>>>(qkvb, vTb, Opart, mlbuf);
    attn_combine_kernel<<<(TSEQ * DMODEL / 4) / 256, 256, 0, stream>>>(Opart, mlbuf, attnb);
    gemm_64_kernel<2><<<dim3(TSEQ / 64, DMODEL / 64), 256, 0, stream>>>(
        attnb, out_wT, out_b, x, x2, TSEQ, DMODEL, DMODEL);
    ln_half_kernel<<<TSEQ, 256, 0, stream>>>(x2, ln2_g, ln2_b, hb);
    gemm_kernel<1><<<dim3(TSEQ / 128, DFF / 128), 256, 0, stream>>>(
        hb, fc1_wT, fc1_b, nullptr, gb, nullptr, TSEQ, DFF, DMODEL);
    gemm_64_kernel<2><<<dim3(TSEQ / 64, DMODEL / 64), 256, 0, stream>>>(
        gb, fc2_wT, fc2_b, x2, (float*)d_out, TSEQ, DMODEL, DFF);
}